// Round 2
// baseline (238.517 us; speedup 1.0000x reference)
//
#include <hip/hip_runtime.h>

typedef unsigned short u16;
typedef __bf16 bf16x8 __attribute__((ext_vector_type(8)));
typedef float floatx4 __attribute__((ext_vector_type(4)));

#define B_   2
#define T_   1024
#define DIM_ 1024
#define H_   8
#define DH_  64
#define E_   5

// c1 column layout: [0,512) q | [512,1024) k | [1024,3584) vexp (h,e,dh)
#define N1   3584
#define M_   2048
#define KOUT 2560   // (h,e,c) contraction dim of output GEMM

__device__ __forceinline__ u16 f2bf(float f) {
  union { float f; unsigned u; } v; v.f = f;
  unsigned r = v.u + 0x7FFFu + ((v.u >> 16) & 1u);
  return (u16)(r >> 16);
}
__device__ __forceinline__ float bf2f(u16 h) {
  union { unsigned u; float f; } v; v.u = ((unsigned)h) << 16;
  return v.f;
}

__device__ __forceinline__ void async_cp16(const void* g, void* l) {
  __builtin_amdgcn_global_load_lds(
      (const __attribute__((address_space(1))) unsigned int*)g,
      (__attribute__((address_space(3))) unsigned int*)l, 16, 0, 0);
}

// ---------------- layout kernels ----------------

__global__ void cvt_x_kernel(const float* __restrict__ x, u16* __restrict__ xb) {
  int i = blockIdx.x * 256 + threadIdx.x;            // 524288 float4 groups
  float4 v = ((const float4*)x)[i];
  union { u16 s[4]; uint2 u; } o;
  o.s[0] = f2bf(v.x); o.s[1] = f2bf(v.y); o.s[2] = f2bf(v.z); o.s[3] = f2bf(v.w);
  ((uint2*)xb)[i] = o.u;
}

// W [1024][N] fp32 -> WT[(n_ofs+n)][1024] bf16  (32x32 LDS tile transpose)
__global__ __launch_bounds__(256)
void transpose_w_kernel(const float* __restrict__ W, u16* __restrict__ WT,
                        int N, int n_ofs) {
  __shared__ float tile[32][33];
  int k0 = blockIdx.x * 32, n0 = blockIdx.y * 32;
  int tx = threadIdx.x & 31, ty = threadIdx.x >> 5;  // 8 rows per pass
  #pragma unroll
  for (int i = 0; i < 32; i += 8)
    tile[ty + i][tx] = W[(size_t)(k0 + ty + i) * N + n0 + tx];
  __syncthreads();
  #pragma unroll
  for (int i = 0; i < 32; i += 8)
    WT[(size_t)(n_ofs + n0 + ty + i) * 1024 + k0 + tx] = f2bf(tile[tx][ty + i]);
}

// Wo [H,E,DIM,DH] fp32 -> WoT [d][(h*E+e)*64+c] bf16 (contiguous-run gather)
__global__ void build_WoT_kernel(const float* __restrict__ Wo, u16* __restrict__ WoT) {
  int i = blockIdx.x * 256 + threadIdx.x;            // 655360 = 2560*1024/4
  int c4 = i & 15;
  int t  = i >> 4;
  int d  = t / 40;
  int he = t - d * 40;
  float4 v = *(const float4*)(Wo + ((size_t)(he * 1024 + d) * 64 + c4 * 4));
  union { u16 s[4]; uint2 u; } o;
  o.s[0] = f2bf(v.x); o.s[1] = f2bf(v.y); o.s[2] = f2bf(v.z); o.s[3] = f2bf(v.w);
  *(uint2*)(WoT + (size_t)d * KOUT + he * 64 + c4 * 4) = o.u;
}

// ---------------- MFMA GEMM (C = A @ B^T), 2-wave blocks, BM=128 BN=64 ----------------

template <int SPLITK, bool OUT_BF16>
__global__ __launch_bounds__(128, 2)
void gemm2w_kernel(const u16* __restrict__ A, const u16* __restrict__ Bm,
                   void* __restrict__ Cv, int N, int Kd) {
  constexpr int BM = 128, BN = 64, BK = 32;
  __shared__ __align__(16) u16 As[BM * BK];   // 8 KB
  __shared__ __align__(16) u16 Bs[BN * BK];   // 4 KB
  const int tid = threadIdx.x;
  const int w = tid >> 6, lane = tid & 63;
  const int ln15 = lane & 15, quad = lane >> 4;
  const int bm0 = blockIdx.x * BM, bn0 = blockIdx.y * BN;
  const int srow = lane >> 2, soff = (lane & 3) * 8;
  const int kchunk = Kd / SPLITK;
  const int kbeg = blockIdx.z * kchunk, kend = kbeg + kchunk;

  floatx4 acc[4][4];
  #pragma unroll
  for (int i = 0; i < 4; ++i)
    #pragma unroll
    for (int j = 0; j < 4; ++j) acc[i][j] = (floatx4){0.f, 0.f, 0.f, 0.f};

  for (int k0 = kbeg; k0 < kend; k0 += BK) {
    __syncthreads();
    #pragma unroll
    for (int j = 0; j < 4; ++j) {             // A: 8 groups of 16 rows
      int i = w * 4 + j;
      async_cp16(A + (size_t)(bm0 + i * 16 + srow) * Kd + k0 + soff,
                 (char*)As + i * 1024);
    }
    #pragma unroll
    for (int j = 0; j < 2; ++j) {             // B: 4 groups of 16 rows
      int i = w * 2 + j;
      async_cp16(Bm + (size_t)(bn0 + i * 16 + srow) * Kd + k0 + soff,
                 (char*)Bs + i * 1024);
    }
    __builtin_amdgcn_s_waitcnt(0);
    __syncthreads();

    bf16x8 af[4], bfr[4];
    #pragma unroll
    for (int mt = 0; mt < 4; ++mt)
      af[mt] = *(const bf16x8*)(As + (w * 64 + mt * 16 + ln15) * BK + quad * 8);
    #pragma unroll
    for (int nt = 0; nt < 4; ++nt)
      bfr[nt] = *(const bf16x8*)(Bs + (nt * 16 + ln15) * BK + quad * 8);
    #pragma unroll
    for (int mt = 0; mt < 4; ++mt)
      #pragma unroll
      for (int nt = 0; nt < 4; ++nt)
        acc[mt][nt] = __builtin_amdgcn_mfma_f32_16x16x32_bf16(af[mt], bfr[nt], acc[mt][nt], 0, 0, 0);
  }

  #pragma unroll
  for (int mt = 0; mt < 4; ++mt)
    #pragma unroll
    for (int nt = 0; nt < 4; ++nt)
      #pragma unroll
      for (int r = 0; r < 4; ++r) {
        int m = bm0 + w * 64 + mt * 16 + quad * 4 + r;
        int n = bn0 + nt * 16 + ln15;
        float v = acc[mt][nt][r];
        if (OUT_BF16) ((u16*)Cv)[(size_t)m * N + n] = f2bf(v);
        else ((float*)Cv)[(size_t)blockIdx.z * M_ * N + (size_t)m * N + n] = v;
      }
}

__global__ void reduce_out_kernel(const float* __restrict__ P, float* __restrict__ out) {
  int i = blockIdx.x * 256 + threadIdx.x;            // 524288 float4 groups
  float4 a = ((const float4*)P)[i];
  float4 b = ((const float4*)(P + (size_t)M_ * 1024))[i];
  float4 r; r.x = a.x + b.x; r.y = a.y + b.y; r.z = a.z + b.z; r.w = a.w + b.w;
  ((float4*)out)[i] = r;
}

// ---------------- routing: fp32 logits (4 rows/block, 3-way K-split) + top-k ----------------

__global__ __launch_bounds__(256)
void routing2_kernel(const float* __restrict__ x, const float* __restrict__ Ws,
                     const float* __restrict__ Wd,
                     float* __restrict__ ssg, float* __restrict__ sdg) {
  __shared__ float xs[4][1025];
  __shared__ float ps[3][4][80];
  __shared__ float lg[4][80];
  const int bt0 = blockIdx.x * 4;
  const int tid = threadIdx.x;

  for (int i = tid; i < 1024; i += 256) {            // 4 rows x 256 float4
    int r = i >> 8, j = i & 255;
    float4 v = ((const float4*)(x + (size_t)(bt0 + r) * 1024))[j];
    xs[r][j * 4 + 0] = v.x; xs[r][j * 4 + 1] = v.y;
    xs[r][j * 4 + 2] = v.z; xs[r][j * 4 + 3] = v.w;
  }
  __syncthreads();

  const int c = tid % 80, ks = tid / 80;             // ks==3 idle (16 threads)
  if (ks < 3) {
    const float* Wp = (c < 40) ? Ws : Wd;
    const int cc = (c < 40) ? c : c - 40;
    const int k0 = ks * 342, k1 = (k0 + 342 < 1024) ? k0 + 342 : 1024;
    float a0 = 0.f, a1 = 0.f, a2 = 0.f, a3 = 0.f;
    #pragma unroll 4
    for (int k = k0; k < k1; ++k) {
      float wv = Wp[k * 40 + cc];
      a0 = fmaf(xs[0][k], wv, a0); a1 = fmaf(xs[1][k], wv, a1);
      a2 = fmaf(xs[2][k], wv, a2); a3 = fmaf(xs[3][k], wv, a3);
    }
    ps[ks][0][c] = a0; ps[ks][1][c] = a1; ps[ks][2][c] = a2; ps[ks][3][c] = a3;
  }
  __syncthreads();

  for (int idx = tid; idx < 320; idx += 256) {
    int r = idx / 80, cc = idx % 80;
    lg[r][cc] = ps[0][r][cc] + ps[1][r][cc] + ps[2][r][cc];
  }
  __syncthreads();

  if (tid < 64) {
    const int r = tid >> 4, h = (tid >> 1) & 7, which = tid & 1;
    float z[E_], g[E_]; bool sel[E_];
    #pragma unroll
    for (int e = 0; e < E_; ++e) {
      z[e] = lg[r][which * 40 + h * E_ + e];         // rank on logits (monotone)
      g[e] = 1.f / (1.f + __expf(-z[e]));
      sel[e] = false;
    }
    #pragma unroll
    for (int it = 0; it < 3; ++it) {
      int bi = 0; float bv = -3e38f;
      #pragma unroll
      for (int e = 0; e < E_; ++e)
        if (!sel[e] && z[e] > bv) { bv = z[e]; bi = e; }
      sel[bi] = true;
    }
    float* dst = (which == 0) ? ssg : sdg;
    #pragma unroll
    for (int e = 0; e < E_; ++e)
      dst[(size_t)(bt0 + r) * 40 + h * E_ + e] =
          (which == 0) ? (sel[e] ? g[e] : 0.f) : (sel[e] ? 1.f : 0.f);
  }
}

// ---------------- fused V-mix + transpose: vexp,ssg -> vT[(b,h,dh)][t] ----------------

__global__ __launch_bounds__(256)
void vmix_tr_kernel(const u16* __restrict__ c1, const float* __restrict__ ssg,
                    u16* __restrict__ vT) {
  __shared__ u16 tile[32][33];
  const int bh = blockIdx.x;
  const int b = bh >> 3, h = bh & 7;
  const int t0 = blockIdx.y * 32, d0 = blockIdx.z * 32;
  const int dh = threadIdx.x & 31, tl = threadIdx.x >> 5;  // 8 t-rows per pass
  #pragma unroll
  for (int i = 0; i < 4; ++i) {
    int trow = tl + i * 8;
    size_t bt = (size_t)b * T_ + t0 + trow;
    const u16* ve = c1 + bt * N1 + 1024 + h * (E_ * 64) + d0 + dh;
    const float* g = ssg + bt * 40 + h * E_;
    float s = 0.f;
    #pragma unroll
    for (int e = 0; e < E_; ++e) s = fmaf(g[e], bf2f(ve[e * 64]), s);
    tile[trow][dh] = f2bf(s);
  }
  __syncthreads();
  #pragma unroll
  for (int i = 0; i < 4; ++i) {
    int d = d0 + tl + i * 8;
    vT[((size_t)(b * H_ + h) * DH_ + d) * T_ + t0 + dh] = tile[dh][tl + i * 8];
  }
}

// ---------------- MFMA flash attention (32-row Q-tiles, 2 waves) + gated A-write ----------------

__global__ __launch_bounds__(128, 2)
void attn_kernel(const u16* __restrict__ c1, const u16* __restrict__ vT,
                 const float* __restrict__ sdg, u16* __restrict__ Ab) {
  __shared__ __align__(16) u16 Qs[32 * 64];
  __shared__ __align__(16) u16 Ks[64 * 64];
  __shared__ __align__(16) u16 Vs[64 * 64];
  __shared__ __align__(16) u16 Ps[32 * 72];   // +8 pad per row
  const int qi = blockIdx.x;                   // 0..31 (32-row q tile)
  const int bh = blockIdx.y;
  const int b = bh >> 3, h = bh & 7;
  const int tid = threadIdx.x;
  const int w = tid >> 6, lane = tid & 63;
  const int ln15 = lane & 15, quad = lane >> 4;
  const int q0 = qi * 32;
  const int r8 = lane >> 3, o8 = (lane & 7) * 8;

  #pragma unroll
  for (int j = 0; j < 2; ++j) {                // Q: 4 groups of 8 rows
    int i = w * 2 + j;
    async_cp16(c1 + (size_t)(b * T_ + q0 + i * 8 + r8) * N1 + h * DH_ + o8,
               (char*)Qs + i * 1024);
  }

  floatx4 O[4];
  float m_st[4], l_st[4];
  #pragma unroll
  for (int j = 0; j < 4; ++j) {
    O[j] = (floatx4){0.f, 0.f, 0.f, 0.f};
    m_st[j] = -3e38f; l_st[j] = 0.f;
  }
  const int qrow = q0 + w * 16 + quad * 4;
  const int nkt = (qi >> 1) + 1;

  for (int kt = 0; kt < nkt; ++kt) {
    const int tk0 = kt * 64;
    __syncthreads();
    #pragma unroll
    for (int j = 0; j < 4; ++j) {              // K,V: 8 groups of 8 rows each
      int i = w * 4 + j;
      async_cp16(c1 + (size_t)(b * T_ + tk0 + i * 8 + r8) * N1 + 512 + h * DH_ + o8,
                 (char*)Ks + i * 1024);
      async_cp16(vT + (size_t)((b * H_ + h) * DH_ + i * 8 + r8) * T_ + tk0 + o8,
                 (char*)Vs + i * 1024);
    }
    __builtin_amdgcn_s_waitcnt(0);
    __syncthreads();

    floatx4 S[4];
    #pragma unroll
    for (int nt = 0; nt < 4; ++nt) S[nt] = (floatx4){0.f, 0.f, 0.f, 0.f};
    #pragma unroll
    for (int ks = 0; ks < 2; ++ks) {
      bf16x8 a = *(const bf16x8*)(Qs + (w * 16 + ln15) * 64 + ks * 32 + quad * 8);
      #pragma unroll
      for (int nt = 0; nt < 4; ++nt) {
        bf16x8 bv = *(const bf16x8*)(Ks + (nt * 16 + ln15) * 64 + ks * 32 + quad * 8);
        S[nt] = __builtin_amdgcn_mfma_f32_16x16x32_bf16(a, bv, S[nt], 0, 0, 0);
      }
    }

    float p[4][4], rmax[4], alpha[4], rsum[4];
    #pragma unroll
    for (int r = 0; r < 4; ++r) rmax[r] = -3e38f;
    #pragma unroll
    for (int nt = 0; nt < 4; ++nt) {
      int col = tk0 + nt * 16 + ln15;
      #pragma unroll
      for (int r = 0; r < 4; ++r) {
        float s = S[nt][r] * 0.125f;          // DH^-0.5
        if (col > qrow + r) s = -3e38f;        // causal
        p[nt][r] = s;
        rmax[r] = fmaxf(rmax[r], s);
      }
    }
    #pragma unroll
    for (int r = 0; r < 4; ++r) {
      #pragma unroll
      for (int off = 1; off < 16; off <<= 1)
        rmax[r] = fmaxf(rmax[r], __shfl_xor(rmax[r], off));
      float mn = fmaxf(m_st[r], rmax[r]);
      alpha[r] = __expf(m_st[r] - mn);
      m_st[r] = mn;
      rsum[r] = 0.f;
    }
    #pragma unroll
    for (int nt = 0; nt < 4; ++nt)
      #pragma unroll
      for (int r = 0; r < 4; ++r) {
        float e = __expf(p[nt][r] - m_st[r]);
        p[nt][r] = e;
        rsum[r] += e;
      }
    #pragma unroll
    for (int r = 0; r < 4; ++r) {
      #pragma unroll
      for (int off = 1; off < 16; off <<= 1)
        rsum[r] += __shfl_xor(rsum[r], off);
      l_st[r] = l_st[r] * alpha[r] + rsum[r];
    }
    #pragma unroll
    for (int nt = 0; nt < 4; ++nt)
      #pragma unroll
      for (int r = 0; r < 4; ++r) O[nt][r] *= alpha[r];
    #pragma unroll
    for (int nt = 0; nt < 4; ++nt)
      #pragma unroll
      for (int r = 0; r < 4; ++r)
        Ps[(w * 16 + quad * 4 + r) * 72 + nt * 16 + ln15] = f2bf(p[nt][r]);
    __syncthreads();

    #pragma unroll
    for (int ks = 0; ks < 2; ++ks) {
      bf16x8 a = *(const bf16x8*)(Ps + (w * 16 + ln15) * 72 + ks * 32 + quad * 8);
      #pragma unroll
      for (int nt = 0; nt < 4; ++nt) {
        bf16x8 bv = *(const bf16x8*)(Vs + (nt * 16 + ln15) * 64 + ks * 32 + quad * 8);
        O[nt] = __builtin_amdgcn_mfma_f32_16x16x32_bf16(a, bv, O[nt], 0, 0, 0);
      }
    }
  }

  #pragma unroll
  for (int r = 0; r < 4; ++r) l_st[r] = 1.f / l_st[r];
  #pragma unroll
  for (int nt = 0; nt < 4; ++nt) {
    int dh = nt * 16 + ln15;
    #pragma unroll
    for (int r = 0; r < 4; ++r) {
      int q = qrow + r;
      size_t bt = (size_t)b * T_ + q;
      float o = O[nt][r] * l_st[r];
      #pragma unroll
      for (int e = 0; e < E_; ++e) {
        float g = sdg[bt * 40 + h * E_ + e];
        Ab[bt * KOUT + (h * E_ + e) * 64 + dh] = f2bf(g * o);
      }
    }
  }
}

// ---------------- launch ----------------

extern "C" void kernel_launch(void* const* d_in, const int* in_sizes, int n_in,
                              void* d_out, int out_size, void* d_ws, size_t ws_size,
                              hipStream_t stream) {
  const float* x  = (const float*)d_in[0];
  const float* Wq = (const float*)d_in[1];
  const float* Wk = (const float*)d_in[2];
  const float* Wv = (const float*)d_in[3];
  const float* Ws = (const float*)d_in[4];
  const float* Wd = (const float*)d_in[5];
  const float* Wo = (const float*)d_in[6];
  float* out = (float*)d_out;

  char* ws = (char*)d_ws;
  u16*   WoT  = (u16*)(ws + 0);            //  5,242,880
  u16*   xb   = (u16*)(ws + 5242880);      //  4,194,304
  u16*   WT   = (u16*)(ws + 9437184);      //  7,340,032  (end 16,777,216)
  u16*   c1   = (u16*)(ws + 16777216);     // 14,680,064  (end 31,457,280)
  float* ssg  = (float*)(ws + 31457280);   //    327,680
  float* sdg  = (float*)(ws + 31784960);   //    327,680
  u16*   vT   = (u16*)(ws + 32112640);     //  2,097,152  (end 34,209,792)
  u16*   Ab   = (u16*)(ws + 34209792);     // 10,485,760  (end 44,695,552)
  // Pk overlaps xb/WT/c1-prefix — all dead by GEMM2 time
  float* Pk   = (float*)(ws + 5242880);    // 16,777,216  (end 22,020,096)

  cvt_x_kernel<<<2048, 256, 0, stream>>>(x, xb);
  transpose_w_kernel<<<dim3(32, 16), 256, 0, stream>>>(Wq, WT, 512, 0);
  transpose_w_kernel<<<dim3(32, 16), 256, 0, stream>>>(Wk, WT, 512, 512);
  transpose_w_kernel<<<dim3(32, 80), 256, 0, stream>>>(Wv, WT, 2560, 1024);
  build_WoT_kernel<<<2560, 256, 0, stream>>>(Wo, WoT);

  // c1 = xb @ WT^T : M=2048, N=3584, K=1024  (896 blocks = 3.5/CU)
  gemm2w_kernel<1, true><<<dim3(16, 56, 1), 128, 0, stream>>>(xb, WT, c1, N1, 1024);

  routing2_kernel<<<512, 256, 0, stream>>>(x, Ws, Wd, ssg, sdg);
  vmix_tr_kernel<<<dim3(16, 32, 2), 256, 0, stream>>>(c1, ssg, vT);

  attn_kernel<<<dim3(32, 16), 128, 0, stream>>>(c1, vT, sdg, Ab);

  // out = Ab @ WoT^T : M=2048, N=1024, K=2560, split-K=2 (512 blocks = 2/CU)
  gemm2w_kernel<2, false><<<dim3(16, 16, 2), 128, 0, stream>>>(Ab, WoT, Pk, 1024, KOUT);
  reduce_out_kernel<<<2048, 256, 0, stream>>>(Pk, out);
}

// Round 3
// 207.967 us; speedup vs baseline: 1.1469x; 1.1469x over previous
//
#include <hip/hip_runtime.h>

typedef unsigned short u16;
typedef __bf16 bf16x8 __attribute__((ext_vector_type(8)));
typedef float floatx4 __attribute__((ext_vector_type(4)));

#define B_   2
#define T_   1024
#define DIM_ 1024
#define H_   8
#define DH_  64
#define E_   5

// c1 column layout: [0,512) q | [512,1024) k | [1024,3584) vexp (h,e,dh)
#define N1   3584
#define M_   2048
#define KOUT 2560   // (h,e,c) contraction dim of output GEMM

__device__ __forceinline__ u16 f2bf(float f) {
  union { float f; unsigned u; } v; v.f = f;
  unsigned r = v.u + 0x7FFFu + ((v.u >> 16) & 1u);
  return (u16)(r >> 16);
}
__device__ __forceinline__ float bf2f(u16 h) {
  union { unsigned u; float f; } v; v.u = ((unsigned)h) << 16;
  return v.f;
}

__device__ __forceinline__ void async_cp16(const void* g, void* l) {
  __builtin_amdgcn_global_load_lds(
      (const __attribute__((address_space(1))) unsigned int*)g,
      (__attribute__((address_space(3))) unsigned int*)l, 16, 0, 0);
}

// ---------------- fused weight transpose: Wq|Wk|Wv [1024][N] fp32 -> WT[n][1024] bf16 ----------------

__global__ __launch_bounds__(256)
void transpose_all_kernel(const float* __restrict__ Wq, const float* __restrict__ Wk,
                          const float* __restrict__ Wv, u16* __restrict__ WT) {
  __shared__ float tile[32][33];
  int k0 = blockIdx.x * 32;
  int nt = blockIdx.y;
  const float* W; int N, n0, nofs;
  if (nt < 16)      { W = Wq; N = 512;  n0 = nt * 32;        nofs = 0; }
  else if (nt < 32) { W = Wk; N = 512;  n0 = (nt - 16) * 32; nofs = 512; }
  else              { W = Wv; N = 2560; n0 = (nt - 32) * 32; nofs = 1024; }
  int tx = threadIdx.x & 31, ty = threadIdx.x >> 5;
  #pragma unroll
  for (int i = 0; i < 32; i += 8)
    tile[ty + i][tx] = W[(size_t)(k0 + ty + i) * N + n0 + tx];
  __syncthreads();
  #pragma unroll
  for (int i = 0; i < 32; i += 8)
    WT[(size_t)(nofs + n0 + ty + i) * 1024 + k0 + tx] = f2bf(tile[tx][ty + i]);
}

// Wo [H,E,DIM,DH] fp32 -> WoT [d][(h*E+e)*64+c] bf16
__global__ void build_WoT_kernel(const float* __restrict__ Wo, u16* __restrict__ WoT) {
  int i = blockIdx.x * 256 + threadIdx.x;            // 655360 groups of 4
  int c4 = i & 15;
  int t  = i >> 4;
  int d  = t / 40;
  int he = t - d * 40;
  float4 v = *(const float4*)(Wo + ((size_t)(he * 1024 + d) * 64 + c4 * 4));
  union { u16 s[4]; uint2 u; } o;
  o.s[0] = f2bf(v.x); o.s[1] = f2bf(v.y); o.s[2] = f2bf(v.z); o.s[3] = f2bf(v.w);
  *(uint2*)(WoT + (size_t)d * KOUT + he * 64 + c4 * 4) = o.u;
}

// ---------------- m97-style MFMA GEMM, 128x128 tile, swizzled LDS, C = A @ B^T ----------------
// bf16 output at C + blockIdx.z * M_*N (split-K partials when SPLITK>1)

template <int SPLITK>
__global__ __launch_bounds__(256)
void gemm4w_kernel(const u16* __restrict__ A, const u16* __restrict__ Bm,
                   u16* __restrict__ C, int N, int Kd) {
  constexpr int BK = 32;
  __shared__ __align__(16) u16 As[128 * BK];
  __shared__ __align__(16) u16 Bs[128 * BK];
  const int tid = threadIdx.x;
  const int w = tid >> 6, lane = tid & 63;
  const int ln15 = lane & 15, quad = lane >> 4;
  const int wm = w >> 1, wn = w & 1;
  const int bm0 = blockIdx.x * 128, bn0 = blockIdx.y * 128;
  const int lrow = lane >> 2;                                  // staging row 0..15
  const int lg8 = (((lane & 3) ^ ((lane >> 3) & 3))) * 8;      // swizzled src chunk
  const int swz = (ln15 >> 1) & 3;                             // read-side key
  const int kchunk = Kd / SPLITK;
  const int kbeg = blockIdx.z * kchunk;

  floatx4 acc[4][4];
  #pragma unroll
  for (int i = 0; i < 4; ++i)
    #pragma unroll
    for (int j = 0; j < 4; ++j) acc[i][j] = (floatx4){0.f, 0.f, 0.f, 0.f};

  for (int k0 = kbeg; k0 < kbeg + kchunk; k0 += BK) {
    __syncthreads();
    #pragma unroll
    for (int j = 0; j < 2; ++j) {
      int i = w * 2 + j;
      async_cp16(A + (size_t)(bm0 + i * 16 + lrow) * Kd + k0 + lg8, (char*)As + i * 1024);
      async_cp16(Bm + (size_t)(bn0 + i * 16 + lrow) * Kd + k0 + lg8, (char*)Bs + i * 1024);
    }
    __builtin_amdgcn_s_waitcnt(0);
    __syncthreads();

    bf16x8 af[4], bf[4];
    #pragma unroll
    for (int mt = 0; mt < 4; ++mt)
      af[mt] = *(const bf16x8*)(As + (wm * 64 + mt * 16 + ln15) * BK + ((quad ^ swz) * 8));
    #pragma unroll
    for (int nt = 0; nt < 4; ++nt)
      bf[nt] = *(const bf16x8*)(Bs + (wn * 64 + nt * 16 + ln15) * BK + ((quad ^ swz) * 8));
    #pragma unroll
    for (int mt = 0; mt < 4; ++mt)
      #pragma unroll
      for (int nt = 0; nt < 4; ++nt)
        acc[mt][nt] = __builtin_amdgcn_mfma_f32_16x16x32_bf16(af[mt], bf[nt], acc[mt][nt], 0, 0, 0);
  }

  u16* Cz = C + (size_t)blockIdx.z * M_ * N;
  #pragma unroll
  for (int mt = 0; mt < 4; ++mt)
    #pragma unroll
    for (int nt = 0; nt < 4; ++nt)
      #pragma unroll
      for (int r = 0; r < 4; ++r) {
        int m = bm0 + wm * 64 + mt * 16 + quad * 4 + r;
        int n = bn0 + wn * 64 + nt * 16 + ln15;
        Cz[(size_t)m * N + n] = f2bf(acc[mt][nt][r]);
      }
}

// reduce 4 bf16 split-K partials -> fp32 out
__global__ void reduce4_kernel(const u16* __restrict__ Pk, float* __restrict__ out) {
  int i = blockIdx.x * 256 + threadIdx.x;            // 262144 groups of 8
  size_t base = (size_t)i * 8;
  float s[8] = {0.f, 0.f, 0.f, 0.f, 0.f, 0.f, 0.f, 0.f};
  #pragma unroll
  for (int z = 0; z < 4; ++z) {
    union { uint4 v; u16 h[8]; } u;
    u.v = *(const uint4*)(Pk + (size_t)z * M_ * 1024 + base);
    #pragma unroll
    for (int c = 0; c < 8; ++c) s[c] += bf2f(u.h[c]);
  }
  float4 o0 = {s[0], s[1], s[2], s[3]}, o1 = {s[4], s[5], s[6], s[7]};
  *(float4*)(out + base) = o0;
  *(float4*)(out + base + 4) = o1;
}

// ---------------- routing (fp32 logits + top-k) fused with x->bf16 convert ----------------

__global__ __launch_bounds__(256)
void routing_cvt_kernel(const float* __restrict__ x, const float* __restrict__ Ws,
                        const float* __restrict__ Wd,
                        float* __restrict__ ssg, float* __restrict__ sdg,
                        u16* __restrict__ xb) {
  __shared__ float xs[4][1025];
  __shared__ float ps[3][4][80];
  __shared__ float lg[4][80];
  const int bt0 = blockIdx.x * 4;
  const int tid = threadIdx.x;

  for (int i = tid; i < 1024; i += 256) {
    int r = i >> 8, j = i & 255;
    float4 v = ((const float4*)(x + (size_t)(bt0 + r) * 1024))[j];
    xs[r][j * 4 + 0] = v.x; xs[r][j * 4 + 1] = v.y;
    xs[r][j * 4 + 2] = v.z; xs[r][j * 4 + 3] = v.w;
  }
  __syncthreads();

  // emit bf16 x
  for (int i = tid; i < 512; i += 256) {
    int r = i >> 7, j2 = i & 127;
    union { u16 s[8]; uint4 v; } o;
    #pragma unroll
    for (int c = 0; c < 8; ++c) o.s[c] = f2bf(xs[r][j2 * 8 + c]);
    *(uint4*)(xb + (size_t)(bt0 + r) * 1024 + j2 * 8) = o.v;
  }

  const int c = tid % 80, ks = tid / 80;
  if (ks < 3) {
    const float* Wp = (c < 40) ? Ws : Wd;
    const int cc = (c < 40) ? c : c - 40;
    const int k0 = ks * 342, k1 = (k0 + 342 < 1024) ? k0 + 342 : 1024;
    float a0 = 0.f, a1 = 0.f, a2 = 0.f, a3 = 0.f;
    #pragma unroll 4
    for (int k = k0; k < k1; ++k) {
      float wv = Wp[k * 40 + cc];
      a0 = fmaf(xs[0][k], wv, a0); a1 = fmaf(xs[1][k], wv, a1);
      a2 = fmaf(xs[2][k], wv, a2); a3 = fmaf(xs[3][k], wv, a3);
    }
    ps[ks][0][c] = a0; ps[ks][1][c] = a1; ps[ks][2][c] = a2; ps[ks][3][c] = a3;
  }
  __syncthreads();

  for (int idx = tid; idx < 320; idx += 256) {
    int r = idx / 80, cc = idx % 80;
    lg[r][cc] = ps[0][r][cc] + ps[1][r][cc] + ps[2][r][cc];
  }
  __syncthreads();

  if (tid < 64) {
    const int r = tid >> 4, h = (tid >> 1) & 7, which = tid & 1;
    float z[E_], g[E_]; bool sel[E_];
    #pragma unroll
    for (int e = 0; e < E_; ++e) {
      z[e] = lg[r][which * 40 + h * E_ + e];
      g[e] = 1.f / (1.f + __expf(-z[e]));
      sel[e] = false;
    }
    #pragma unroll
    for (int it = 0; it < 3; ++it) {
      int bi = 0; float bv = -3e38f;
      #pragma unroll
      for (int e = 0; e < E_; ++e)
        if (!sel[e] && z[e] > bv) { bv = z[e]; bi = e; }
      sel[bi] = true;
    }
    float* dst = (which == 0) ? ssg : sdg;
    #pragma unroll
    for (int e = 0; e < E_; ++e)
      dst[(size_t)(bt0 + r) * 40 + h * E_ + e] =
          (which == 0) ? (sel[e] ? g[e] : 0.f) : (sel[e] ? 1.f : 0.f);
  }
}

// ---------------- fused V-mix + transpose: vexp,ssg -> vT[(b,h,dh)][t] ----------------

__global__ __launch_bounds__(256)
void vmix_tr_kernel(const u16* __restrict__ c1, const float* __restrict__ ssg,
                    u16* __restrict__ vT) {
  __shared__ u16 tile[32][33];
  const int bh = blockIdx.x;
  const int b = bh >> 3, h = bh & 7;
  const int t0 = blockIdx.y * 32, d0 = blockIdx.z * 32;
  const int dh = threadIdx.x & 31, tl = threadIdx.x >> 5;
  #pragma unroll
  for (int i = 0; i < 4; ++i) {
    int trow = tl + i * 8;
    size_t bt = (size_t)b * T_ + t0 + trow;
    const u16* ve = c1 + bt * N1 + 1024 + h * (E_ * 64) + d0 + dh;
    const float* g = ssg + bt * 40 + h * E_;
    float s = 0.f;
    #pragma unroll
    for (int e = 0; e < E_; ++e) s = fmaf(g[e], bf2f(ve[e * 64]), s);
    tile[trow][dh] = f2bf(s);
  }
  __syncthreads();
  #pragma unroll
  for (int i = 0; i < 4; ++i) {
    int d = d0 + tl + i * 8;
    vT[((size_t)(b * H_ + h) * DH_ + d) * T_ + t0 + dh] = tile[dh][tl + i * 8];
  }
}

// ---------------- flash attention: 32-row Q tiles, wave-pairs split kt, swizzled LDS ----------------

__global__ __launch_bounds__(256)
void attn_kernel(const u16* __restrict__ c1, const u16* __restrict__ vT,
                 const float* __restrict__ sdg, u16* __restrict__ Ab) {
  __shared__ __align__(16) u16 Qs[32 * 64];        //  4 KB
  __shared__ __align__(16) u16 Ks[2][64 * 64];     // 16 KB
  __shared__ __align__(16) u16 Vs[2][64 * 64];     // 16 KB
  __shared__ __align__(16) u16 Ps[2][32 * 72];     //  9 KB
  __shared__ float Om[2][32][68];                  // 17.4 KB
  __shared__ float Ml[2][32], Ll[2][32];
  const int qi = blockIdx.x;                        // 0..31
  const int bh = blockIdx.y;
  const int b = bh >> 3, h = bh & 7;
  const int tid = threadIdx.x;
  const int w = tid >> 6, lane = tid & 63;
  const int ln15 = lane & 15, quad = lane >> 4;
  const int hh = w >> 1, wq = w & 1;
  const int q0 = qi * 32;
  const int nkt = (qi >> 1) + 1;
  const int h0n = (nkt + 1) >> 1;                   // tiles in half 0
  const int r8 = lane >> 3;
  const int g8 = ((lane & 7) ^ ((lane >> 3) & 7)) * 8;  // swizzled src chunk
  const int swz = ln15 & 7;                              // read-side key

  // Q staging: wave w loads rows [w*8, w*8+8)
  async_cp16(c1 + (size_t)(b * T_ + q0 + w * 8 + r8) * N1 + h * DH_ + g8,
             (char*)Qs + w * 1024);

  floatx4 O[4];
  float m_st[4], l_st[4];
  #pragma unroll
  for (int j = 0; j < 4; ++j) {
    O[j] = (floatx4){0.f, 0.f, 0.f, 0.f};
    m_st[j] = -3e38f; l_st[j] = 0.f;
  }
  const int qrow = q0 + wq * 16 + quad * 4;

  for (int j = 0; j < h0n; ++j) {
    const int myt = hh ? (h0n + j) : j;             // this wave-pair's tile
    const bool act = (hh == 0) || (h0n + j < nkt);
    __syncthreads();
    // staging: w0->Ks[0], w1->Vs[0], w2->Ks[1], w3->Vs[1]
    if (w < 2 || h0n + j < nkt) {
      const int tk = (w < 2 ? j : h0n + j) * 64;
      if ((w & 1) == 0) {
        #pragma unroll
        for (int i = 0; i < 8; ++i)
          async_cp16(c1 + (size_t)(b * T_ + tk + i * 8 + r8) * N1 + 512 + h * DH_ + g8,
                     (char*)Ks[w >> 1] + i * 1024);
      } else {
        #pragma unroll
        for (int i = 0; i < 8; ++i)
          async_cp16(vT + (size_t)((b * H_ + h) * DH_ + i * 8 + r8) * T_ + tk + g8,
                     (char*)Vs[w >> 1] + i * 1024);
      }
    }
    __builtin_amdgcn_s_waitcnt(0);
    __syncthreads();

    float p[4][4];
    if (act) {
      const int tk0 = myt * 64;
      floatx4 S[4];
      #pragma unroll
      for (int nt = 0; nt < 4; ++nt) S[nt] = (floatx4){0.f, 0.f, 0.f, 0.f};
      #pragma unroll
      for (int ks = 0; ks < 2; ++ks) {
        bf16x8 a = *(const bf16x8*)(Qs + (wq * 16 + ln15) * 64 + (((ks * 4 + quad) ^ swz)) * 8);
        #pragma unroll
        for (int nt = 0; nt < 4; ++nt) {
          bf16x8 bv = *(const bf16x8*)(&Ks[hh][(nt * 16 + ln15) * 64 + (((ks * 4 + quad) ^ swz)) * 8]);
          S[nt] = __builtin_amdgcn_mfma_f32_16x16x32_bf16(a, bv, S[nt], 0, 0, 0);
        }
      }
      float rmax[4], alpha[4], rsum[4];
      #pragma unroll
      for (int r = 0; r < 4; ++r) rmax[r] = -3e38f;
      #pragma unroll
      for (int nt = 0; nt < 4; ++nt) {
        int col = tk0 + nt * 16 + ln15;
        #pragma unroll
        for (int r = 0; r < 4; ++r) {
          float s = S[nt][r] * 0.125f;
          if (col > qrow + r) s = -3e38f;
          p[nt][r] = s;
          rmax[r] = fmaxf(rmax[r], s);
        }
      }
      #pragma unroll
      for (int r = 0; r < 4; ++r) {
        #pragma unroll
        for (int off = 1; off < 16; off <<= 1)
          rmax[r] = fmaxf(rmax[r], __shfl_xor(rmax[r], off));
        float mn = fmaxf(m_st[r], rmax[r]);
        alpha[r] = __expf(m_st[r] - mn);
        m_st[r] = mn;
        rsum[r] = 0.f;
      }
      #pragma unroll
      for (int nt = 0; nt < 4; ++nt)
        #pragma unroll
        for (int r = 0; r < 4; ++r) {
          float e = __expf(p[nt][r] - m_st[r]);
          p[nt][r] = e;
          rsum[r] += e;
        }
      #pragma unroll
      for (int r = 0; r < 4; ++r) {
        #pragma unroll
        for (int off = 1; off < 16; off <<= 1)
          rsum[r] += __shfl_xor(rsum[r], off);
        l_st[r] = l_st[r] * alpha[r] + rsum[r];
      }
      #pragma unroll
      for (int nt = 0; nt < 4; ++nt)
        #pragma unroll
        for (int r = 0; r < 4; ++r) O[nt][r] *= alpha[r];
      #pragma unroll
      for (int nt = 0; nt < 4; ++nt)
        #pragma unroll
        for (int r = 0; r < 4; ++r)
          Ps[hh][(wq * 16 + quad * 4 + r) * 72 + nt * 16 + ln15] = f2bf(p[nt][r]);
    }
    __syncthreads();
    if (act) {
      #pragma unroll
      for (int ks = 0; ks < 2; ++ks) {
        bf16x8 a = *(const bf16x8*)(&Ps[hh][(wq * 16 + ln15) * 72 + ks * 32 + quad * 8]);
        #pragma unroll
        for (int nt = 0; nt < 4; ++nt) {
          bf16x8 bv = *(const bf16x8*)(&Vs[hh][(nt * 16 + ln15) * 64 + (((ks * 4 + quad) ^ swz)) * 8]);
          O[nt] = __builtin_amdgcn_mfma_f32_16x16x32_bf16(a, bv, O[nt], 0, 0, 0);
        }
      }
    }
  }

  // publish per-half partials
  #pragma unroll
  for (int nt = 0; nt < 4; ++nt)
    #pragma unroll
    for (int r = 0; r < 4; ++r)
      Om[hh][wq * 16 + quad * 4 + r][nt * 16 + ln15] = O[nt][r];
  if (ln15 == 0) {
    #pragma unroll
    for (int r = 0; r < 4; ++r) {
      Ml[hh][wq * 16 + quad * 4 + r] = m_st[r];
      Ll[hh][wq * 16 + quad * 4 + r] = l_st[r];
    }
  }
  __syncthreads();

  // merge halves + gate + write Ab
  const int rr = tid >> 3, cg = (tid & 7) * 8;
  float m0 = Ml[0][rr], m1 = Ml[1][rr];
  float l0 = Ll[0][rr], l1 = Ll[1][rr];
  float m = fmaxf(m0, m1);
  float a0 = __expf(m0 - m), a1 = __expf(m1 - m);
  float inv = 1.f / (l0 * a0 + l1 * a1);
  float oc[8];
  #pragma unroll
  for (int cc = 0; cc < 8; ++cc)
    oc[cc] = (Om[0][rr][cg + cc] * a0 + Om[1][rr][cg + cc] * a1) * inv;
  size_t bt = (size_t)b * T_ + q0 + rr;
  #pragma unroll
  for (int e = 0; e < E_; ++e) {
    float g = sdg[bt * 40 + h * E_ + e];
    union { u16 s[8]; uint4 v; } o;
    #pragma unroll
    for (int cc = 0; cc < 8; ++cc) o.s[cc] = f2bf(g * oc[cc]);
    *(uint4*)(Ab + bt * KOUT + (h * E_ + e) * 64 + cg) = o.v;
  }
}

// ---------------- launch ----------------

extern "C" void kernel_launch(void* const* d_in, const int* in_sizes, int n_in,
                              void* d_out, int out_size, void* d_ws, size_t ws_size,
                              hipStream_t stream) {
  const float* x  = (const float*)d_in[0];
  const float* Wq = (const float*)d_in[1];
  const float* Wk = (const float*)d_in[2];
  const float* Wv = (const float*)d_in[3];
  const float* Ws = (const float*)d_in[4];
  const float* Wd = (const float*)d_in[5];
  const float* Wo = (const float*)d_in[6];
  float* out = (float*)d_out;

  char* ws = (char*)d_ws;
  u16*   WoT  = (u16*)(ws + 0);            //  5,242,880
  u16*   xb   = (u16*)(ws + 5242880);      //  4,194,304
  u16*   WT   = (u16*)(ws + 9437184);      //  7,340,032  (end 16,777,216)
  u16*   c1   = (u16*)(ws + 16777216);     // 14,680,064  (end 31,457,280)
  float* ssg  = (float*)(ws + 31457280);   //    327,680
  float* sdg  = (float*)(ws + 31784960);   //    327,680
  u16*   vT   = (u16*)(ws + 32112640);     //  2,097,152  (end 34,209,792)
  u16*   Ab   = (u16*)(ws + 34209792);     // 10,485,760  (end 44,695,552)
  u16*   Pk   = (u16*)(ws + 46137344);     // 16,777,216  (end 62,914,560)

  routing_cvt_kernel<<<512, 256, 0, stream>>>(x, Ws, Wd, ssg, sdg, xb);
  transpose_all_kernel<<<dim3(32, 112), 256, 0, stream>>>(Wq, Wk, Wv, WT);
  build_WoT_kernel<<<2560, 256, 0, stream>>>(Wo, WoT);

  // c1 = xb @ WT^T : M=2048, N=3584, K=1024
  gemm4w_kernel<1><<<dim3(16, 28, 1), 256, 0, stream>>>(xb, WT, c1, N1, 1024);

  vmix_tr_kernel<<<dim3(16, 32, 2), 256, 0, stream>>>(c1, ssg, vT);

  attn_kernel<<<dim3(32, 16), 256, 0, stream>>>(c1, vT, sdg, Ab);

  // out = Ab @ WoT^T : M=2048, N=1024, K=2560, split-K=4, bf16 partials
  gemm4w_kernel<4><<<dim3(16, 8, 4), 256, 0, stream>>>(Ab, WoT, Pk, 1024, KOUT);
  reduce4_kernel<<<1024, 256, 0, stream>>>(Pk, out);
}

// Round 4
// 192.492 us; speedup vs baseline: 1.2391x; 1.0804x over previous
//
#include <hip/hip_runtime.h>

typedef unsigned short u16;
typedef __bf16 bf16x8 __attribute__((ext_vector_type(8)));
typedef float floatx4 __attribute__((ext_vector_type(4)));

#define B_   2
#define T_   1024
#define DIM_ 1024
#define H_   8
#define DH_  64
#define E_   5

// c1 column layout: [0,512) q | [512,1024) k | [1024,3584) vexp (h,e,dh)
#define N1   3584
#define M_   2048
#define KOUT 2560   // (h,e,c) contraction dim of output GEMM

__device__ __forceinline__ u16 f2bf(float f) {
  union { float f; unsigned u; } v; v.f = f;
  unsigned r = v.u + 0x7FFFu + ((v.u >> 16) & 1u);
  return (u16)(r >> 16);
}
__device__ __forceinline__ float bf2f(u16 h) {
  union { unsigned u; float f; } v; v.u = ((unsigned)h) << 16;
  return v.f;
}

__device__ __forceinline__ void async_cp16(const void* g, void* l) {
  __builtin_amdgcn_global_load_lds(
      (const __attribute__((address_space(1))) unsigned int*)g,
      (__attribute__((address_space(3))) unsigned int*)l, 16, 0, 0);
}

// ---------------- fused weight transpose: Wq|Wk|Wv [1024][N] fp32 -> WT[n][1024] bf16 ----------------

__global__ __launch_bounds__(256)
void transpose_all_kernel(const float* __restrict__ Wq, const float* __restrict__ Wk,
                          const float* __restrict__ Wv, u16* __restrict__ WT) {
  __shared__ float tile[32][33];
  int k0 = blockIdx.x * 32;
  int nt = blockIdx.y;
  const float* W; int N, n0, nofs;
  if (nt < 16)      { W = Wq; N = 512;  n0 = nt * 32;        nofs = 0; }
  else if (nt < 32) { W = Wk; N = 512;  n0 = (nt - 16) * 32; nofs = 512; }
  else              { W = Wv; N = 2560; n0 = (nt - 32) * 32; nofs = 1024; }
  int tx = threadIdx.x & 31, ty = threadIdx.x >> 5;
  #pragma unroll
  for (int i = 0; i < 32; i += 8)
    tile[ty + i][tx] = W[(size_t)(k0 + ty + i) * N + n0 + tx];
  __syncthreads();
  #pragma unroll
  for (int i = 0; i < 32; i += 8)
    WT[(size_t)(nofs + n0 + ty + i) * 1024 + k0 + tx] = f2bf(tile[tx][ty + i]);
}

// Wo [H,E,DIM,DH] fp32 -> WoT [d][(h*E+e)*64+c] bf16
__global__ void build_WoT_kernel(const float* __restrict__ Wo, u16* __restrict__ WoT) {
  int i = blockIdx.x * 256 + threadIdx.x;            // 655360 groups of 4
  int c4 = i & 15;
  int t  = i >> 4;
  int d  = t / 40;
  int he = t - d * 40;
  float4 v = *(const float4*)(Wo + ((size_t)(he * 1024 + d) * 64 + c4 * 4));
  union { u16 s[4]; uint2 u; } o;
  o.s[0] = f2bf(v.x); o.s[1] = f2bf(v.y); o.s[2] = f2bf(v.z); o.s[3] = f2bf(v.w);
  *(uint2*)(WoT + (size_t)d * KOUT + he * 64 + c4 * 4) = o.u;
}

// ---------------- fp32 logits GEMM (split-K=8) + fused x->bf16 emit ----------------
// logits[bt][c] = x[bt][:] . W[:][c], c<40 -> Ws, c>=40 -> Wd. Partials Pl[z][bt][80].

__global__ __launch_bounds__(256)
void logits_kernel(const float* __restrict__ x, const float* __restrict__ Ws,
                   const float* __restrict__ Wd, float* __restrict__ Pl,
                   u16* __restrict__ xb) {
  __shared__ float xs[16][68];   // [kk][row], pad 64->68
  __shared__ float wt[16][80];
  const int tid = threadIdx.x;
  const int m0 = blockIdx.x * 64;
  const int kbeg = blockIdx.y * 128;
  const int tx = tid & 15, ty = tid >> 4;      // cols 5*tx.., rows 4*ty..
  const int srow = tid >> 2, skq = tid & 3;    // x staging

  float acc[4][5];
  #pragma unroll
  for (int r = 0; r < 4; ++r)
    #pragma unroll
    for (int c = 0; c < 5; ++c) acc[r][c] = 0.f;

  for (int s = 0; s < 8; ++s) {
    const int k0 = kbeg + s * 16;
    __syncthreads();
    // x tile: 64 rows x 16 k (fp32), also emit bf16 xb
    {
      float4 v = *(const float4*)(x + (size_t)(m0 + srow) * 1024 + k0 + skq * 4);
      xs[skq * 4 + 0][srow] = v.x; xs[skq * 4 + 1][srow] = v.y;
      xs[skq * 4 + 2][srow] = v.z; xs[skq * 4 + 3][srow] = v.w;
      union { u16 h[4]; uint2 u; } o;
      o.h[0] = f2bf(v.x); o.h[1] = f2bf(v.y); o.h[2] = f2bf(v.z); o.h[3] = f2bf(v.w);
      *(uint2*)(xb + (size_t)(m0 + srow) * 1024 + k0 + skq * 4) = o.u;
    }
    // W tile: 16 k-rows x 80 cols
    #pragma unroll
    for (int j = 0; j < 5; ++j) {
      int f = j * 256 + tid;                   // 0..1279, coalesced per j
      int kk = f / 80, c = f - kk * 80;
      wt[kk][c] = (c < 40) ? Ws[(size_t)(k0 + kk) * 40 + c]
                           : Wd[(size_t)(k0 + kk) * 40 + c - 40];
    }
    __syncthreads();

    #pragma unroll
    for (int kk = 0; kk < 16; ++kk) {
      float4 xv = *(const float4*)(&xs[kk][ty * 4]);
      float xr[4] = {xv.x, xv.y, xv.z, xv.w};
      #pragma unroll
      for (int c = 0; c < 5; ++c) {
        float wv = wt[kk][tx * 5 + c];
        #pragma unroll
        for (int r = 0; r < 4; ++r) acc[r][c] = fmaf(xr[r], wv, acc[r][c]);
      }
    }
  }

  float* P = Pl + (size_t)blockIdx.y * M_ * 80;
  #pragma unroll
  for (int r = 0; r < 4; ++r)
    #pragma unroll
    for (int c = 0; c < 5; ++c)
      P[(size_t)(m0 + ty * 4 + r) * 80 + tx * 5 + c] = acc[r][c];
}

// reduce 8 partials + sigmoid + top-k -> ssg (soft gates), sdg (0/1 gates)
__global__ __launch_bounds__(256)
void topk_kernel(const float* __restrict__ Pl, float* __restrict__ ssg,
                 float* __restrict__ sdg) {
  __shared__ float lg[16][80];
  const int bt0 = blockIdx.x * 16;
  const int tid = threadIdx.x;
  #pragma unroll
  for (int j = 0; j < 5; ++j) {
    int f = j * 256 + tid;                     // 0..1279
    int r = f / 80, c = f - r * 80;
    float s = 0.f;
    #pragma unroll
    for (int z = 0; z < 8; ++z)
      s += Pl[(size_t)z * M_ * 80 + (size_t)(bt0 + r) * 80 + c];
    lg[r][c] = s;
  }
  __syncthreads();

  const int r = tid >> 4, h = (tid >> 1) & 7, side = tid & 1;
  float z[E_], g[E_]; bool sel[E_];
  #pragma unroll
  for (int e = 0; e < E_; ++e) {
    z[e] = lg[r][side * 40 + h * E_ + e];      // rank on logits (monotone)
    g[e] = 1.f / (1.f + __expf(-z[e]));
    sel[e] = false;
  }
  #pragma unroll
  for (int it = 0; it < 3; ++it) {
    int bi = 0; float bv = -3e38f;
    #pragma unroll
    for (int e = 0; e < E_; ++e)
      if (!sel[e] && z[e] > bv) { bv = z[e]; bi = e; }
    sel[bi] = true;
  }
  float* dst = (side == 0) ? ssg : sdg;
  #pragma unroll
  for (int e = 0; e < E_; ++e)
    dst[(size_t)(bt0 + r) * 40 + h * E_ + e] =
        (side == 0) ? (sel[e] ? g[e] : 0.f) : (sel[e] ? 1.f : 0.f);
}

// ---------------- m97-style MFMA GEMM, 128x128 tile, swizzled LDS, C = A @ B^T ----------------
// bf16 output at C + blockIdx.z * M_*N (split-K partials when SPLITK>1)

template <int SPLITK>
__global__ __launch_bounds__(256)
void gemm4w_kernel(const u16* __restrict__ A, const u16* __restrict__ Bm,
                   u16* __restrict__ C, int N, int Kd) {
  constexpr int BK = 32;
  __shared__ __align__(16) u16 As[128 * BK];
  __shared__ __align__(16) u16 Bs[128 * BK];
  const int tid = threadIdx.x;
  const int w = tid >> 6, lane = tid & 63;
  const int ln15 = lane & 15, quad = lane >> 4;
  const int wm = w >> 1, wn = w & 1;
  const int bm0 = blockIdx.x * 128, bn0 = blockIdx.y * 128;
  const int lrow = lane >> 2;                                  // staging row 0..15
  const int lg8 = (((lane & 3) ^ ((lane >> 3) & 3))) * 8;      // swizzled src chunk
  const int swz = (ln15 >> 1) & 3;                             // read-side key
  const int kchunk = Kd / SPLITK;
  const int kbeg = blockIdx.z * kchunk;

  floatx4 acc[4][4];
  #pragma unroll
  for (int i = 0; i < 4; ++i)
    #pragma unroll
    for (int j = 0; j < 4; ++j) acc[i][j] = (floatx4){0.f, 0.f, 0.f, 0.f};

  for (int k0 = kbeg; k0 < kbeg + kchunk; k0 += BK) {
    __syncthreads();
    #pragma unroll
    for (int j = 0; j < 2; ++j) {
      int i = w * 2 + j;
      async_cp16(A + (size_t)(bm0 + i * 16 + lrow) * Kd + k0 + lg8, (char*)As + i * 1024);
      async_cp16(Bm + (size_t)(bn0 + i * 16 + lrow) * Kd + k0 + lg8, (char*)Bs + i * 1024);
    }
    __builtin_amdgcn_s_waitcnt(0);
    __syncthreads();

    bf16x8 af[4], bf[4];
    #pragma unroll
    for (int mt = 0; mt < 4; ++mt)
      af[mt] = *(const bf16x8*)(As + (wm * 64 + mt * 16 + ln15) * BK + ((quad ^ swz) * 8));
    #pragma unroll
    for (int nt = 0; nt < 4; ++nt)
      bf[nt] = *(const bf16x8*)(Bs + (wn * 64 + nt * 16 + ln15) * BK + ((quad ^ swz) * 8));
    #pragma unroll
    for (int mt = 0; mt < 4; ++mt)
      #pragma unroll
      for (int nt = 0; nt < 4; ++nt)
        acc[mt][nt] = __builtin_amdgcn_mfma_f32_16x16x32_bf16(af[mt], bf[nt], acc[mt][nt], 0, 0, 0);
  }

  u16* Cz = C + (size_t)blockIdx.z * M_ * N;
  #pragma unroll
  for (int mt = 0; mt < 4; ++mt)
    #pragma unroll
    for (int nt = 0; nt < 4; ++nt)
      #pragma unroll
      for (int r = 0; r < 4; ++r) {
        int m = bm0 + wm * 64 + mt * 16 + quad * 4 + r;
        int n = bn0 + wn * 64 + nt * 16 + ln15;
        Cz[(size_t)m * N + n] = f2bf(acc[mt][nt][r]);
      }
}

// reduce 4 bf16 split-K partials -> fp32 out
__global__ void reduce4_kernel(const u16* __restrict__ Pk, float* __restrict__ out) {
  int i = blockIdx.x * 256 + threadIdx.x;            // 262144 groups of 8
  size_t base = (size_t)i * 8;
  float s[8] = {0.f, 0.f, 0.f, 0.f, 0.f, 0.f, 0.f, 0.f};
  #pragma unroll
  for (int z = 0; z < 4; ++z) {
    union { uint4 v; u16 h[8]; } u;
    u.v = *(const uint4*)(Pk + (size_t)z * M_ * 1024 + base);
    #pragma unroll
    for (int c = 0; c < 8; ++c) s[c] += bf2f(u.h[c]);
  }
  float4 o0 = {s[0], s[1], s[2], s[3]}, o1 = {s[4], s[5], s[6], s[7]};
  *(float4*)(out + base) = o0;
  *(float4*)(out + base + 4) = o1;
}

// ---------------- fused V-mix + transpose: vexp,ssg -> vT[(b,h,dh)][t] ----------------

__global__ __launch_bounds__(256)
void vmix_tr_kernel(const u16* __restrict__ c1, const float* __restrict__ ssg,
                    u16* __restrict__ vT) {
  __shared__ u16 tile[32][33];
  const int bh = blockIdx.x;
  const int b = bh >> 3, h = bh & 7;
  const int t0 = blockIdx.y * 32, d0 = blockIdx.z * 32;
  const int dh = threadIdx.x & 31, tl = threadIdx.x >> 5;
  #pragma unroll
  for (int i = 0; i < 4; ++i) {
    int trow = tl + i * 8;
    size_t bt = (size_t)b * T_ + t0 + trow;
    const u16* ve = c1 + bt * N1 + 1024 + h * (E_ * 64) + d0 + dh;
    const float* g = ssg + bt * 40 + h * E_;
    float s = 0.f;
    #pragma unroll
    for (int e = 0; e < E_; ++e) s = fmaf(g[e], bf2f(ve[e * 64]), s);
    tile[trow][dh] = f2bf(s);
  }
  __syncthreads();
  #pragma unroll
  for (int i = 0; i < 4; ++i) {
    int d = d0 + tl + i * 8;
    vT[((size_t)(b * H_ + h) * DH_ + d) * T_ + t0 + dh] = tile[dh][tl + i * 8];
  }
}

// ---------------- flash attention: 32-row Q tiles, wave-pairs split kt, swizzled LDS ----------------

__global__ __launch_bounds__(256)
void attn_kernel(const u16* __restrict__ c1, const u16* __restrict__ vT,
                 const float* __restrict__ sdg, u16* __restrict__ Ab) {
  __shared__ __align__(16) u16 Qs[32 * 64];        //  4 KB
  __shared__ __align__(16) u16 Ks[2][64 * 64];     // 16 KB
  __shared__ __align__(16) u16 Vs[2][64 * 64];     // 16 KB
  __shared__ __align__(16) u16 Ps[2][32 * 72];     //  9 KB
  __shared__ float Om[2][32][68];                  // 17.4 KB
  __shared__ float Ml[2][32], Ll[2][32];
  const int qi = blockIdx.x;                        // 0..31
  const int bh = blockIdx.y;
  const int b = bh >> 3, h = bh & 7;
  const int tid = threadIdx.x;
  const int w = tid >> 6, lane = tid & 63;
  const int ln15 = lane & 15, quad = lane >> 4;
  const int hh = w >> 1, wq = w & 1;
  const int q0 = qi * 32;
  const int nkt = (qi >> 1) + 1;
  const int h0n = (nkt + 1) >> 1;                   // tiles in half 0
  const int r8 = lane >> 3;
  const int g8 = ((lane & 7) ^ ((lane >> 3) & 7)) * 8;  // swizzled src chunk
  const int swz = ln15 & 7;                              // read-side key

  // Q staging: wave w loads rows [w*8, w*8+8)
  async_cp16(c1 + (size_t)(b * T_ + q0 + w * 8 + r8) * N1 + h * DH_ + g8,
             (char*)Qs + w * 1024);

  floatx4 O[4];
  float m_st[4], l_st[4];
  #pragma unroll
  for (int j = 0; j < 4; ++j) {
    O[j] = (floatx4){0.f, 0.f, 0.f, 0.f};
    m_st[j] = -3e38f; l_st[j] = 0.f;
  }
  const int qrow = q0 + wq * 16 + quad * 4;

  for (int j = 0; j < h0n; ++j) {
    const int myt = hh ? (h0n + j) : j;             // this wave-pair's tile
    const bool act = (hh == 0) || (h0n + j < nkt);
    __syncthreads();
    // staging: w0->Ks[0], w1->Vs[0], w2->Ks[1], w3->Vs[1]
    if (w < 2 || h0n + j < nkt) {
      const int tk = (w < 2 ? j : h0n + j) * 64;
      if ((w & 1) == 0) {
        #pragma unroll
        for (int i = 0; i < 8; ++i)
          async_cp16(c1 + (size_t)(b * T_ + tk + i * 8 + r8) * N1 + 512 + h * DH_ + g8,
                     (char*)Ks[w >> 1] + i * 1024);
      } else {
        #pragma unroll
        for (int i = 0; i < 8; ++i)
          async_cp16(vT + (size_t)((b * H_ + h) * DH_ + i * 8 + r8) * T_ + tk + g8,
                     (char*)Vs[w >> 1] + i * 1024);
      }
    }
    __builtin_amdgcn_s_waitcnt(0);
    __syncthreads();

    float p[4][4];
    if (act) {
      const int tk0 = myt * 64;
      floatx4 S[4];
      #pragma unroll
      for (int nt = 0; nt < 4; ++nt) S[nt] = (floatx4){0.f, 0.f, 0.f, 0.f};
      #pragma unroll
      for (int ks = 0; ks < 2; ++ks) {
        bf16x8 a = *(const bf16x8*)(Qs + (wq * 16 + ln15) * 64 + (((ks * 4 + quad) ^ swz)) * 8);
        #pragma unroll
        for (int nt = 0; nt < 4; ++nt) {
          bf16x8 bv = *(const bf16x8*)(&Ks[hh][(nt * 16 + ln15) * 64 + (((ks * 4 + quad) ^ swz)) * 8]);
          S[nt] = __builtin_amdgcn_mfma_f32_16x16x32_bf16(a, bv, S[nt], 0, 0, 0);
        }
      }
      float rmax[4], alpha[4], rsum[4];
      #pragma unroll
      for (int r = 0; r < 4; ++r) rmax[r] = -3e38f;
      #pragma unroll
      for (int nt = 0; nt < 4; ++nt) {
        int col = tk0 + nt * 16 + ln15;
        #pragma unroll
        for (int r = 0; r < 4; ++r) {
          float s = S[nt][r] * 0.125f;
          if (col > qrow + r) s = -3e38f;
          p[nt][r] = s;
          rmax[r] = fmaxf(rmax[r], s);
        }
      }
      #pragma unroll
      for (int r = 0; r < 4; ++r) {
        #pragma unroll
        for (int off = 1; off < 16; off <<= 1)
          rmax[r] = fmaxf(rmax[r], __shfl_xor(rmax[r], off));
        float mn = fmaxf(m_st[r], rmax[r]);
        alpha[r] = __expf(m_st[r] - mn);
        m_st[r] = mn;
        rsum[r] = 0.f;
      }
      #pragma unroll
      for (int nt = 0; nt < 4; ++nt)
        #pragma unroll
        for (int r = 0; r < 4; ++r) {
          float e = __expf(p[nt][r] - m_st[r]);
          p[nt][r] = e;
          rsum[r] += e;
        }
      #pragma unroll
      for (int r = 0; r < 4; ++r) {
        #pragma unroll
        for (int off = 1; off < 16; off <<= 1)
          rsum[r] += __shfl_xor(rsum[r], off);
        l_st[r] = l_st[r] * alpha[r] + rsum[r];
      }
      #pragma unroll
      for (int nt = 0; nt < 4; ++nt)
        #pragma unroll
        for (int r = 0; r < 4; ++r) O[nt][r] *= alpha[r];
      #pragma unroll
      for (int nt = 0; nt < 4; ++nt)
        #pragma unroll
        for (int r = 0; r < 4; ++r)
          Ps[hh][(wq * 16 + quad * 4 + r) * 72 + nt * 16 + ln15] = f2bf(p[nt][r]);
    }
    __syncthreads();
    if (act) {
      #pragma unroll
      for (int ks = 0; ks < 2; ++ks) {
        bf16x8 a = *(const bf16x8*)(&Ps[hh][(wq * 16 + ln15) * 72 + ks * 32 + quad * 8]);
        #pragma unroll
        for (int nt = 0; nt < 4; ++nt) {
          bf16x8 bv = *(const bf16x8*)(&Vs[hh][(nt * 16 + ln15) * 64 + (((ks * 4 + quad) ^ swz)) * 8]);
          O[nt] = __builtin_amdgcn_mfma_f32_16x16x32_bf16(a, bv, O[nt], 0, 0, 0);
        }
      }
    }
  }

  // publish per-half partials
  #pragma unroll
  for (int nt = 0; nt < 4; ++nt)
    #pragma unroll
    for (int r = 0; r < 4; ++r)
      Om[hh][wq * 16 + quad * 4 + r][nt * 16 + ln15] = O[nt][r];
  if (ln15 == 0) {
    #pragma unroll
    for (int r = 0; r < 4; ++r) {
      Ml[hh][wq * 16 + quad * 4 + r] = m_st[r];
      Ll[hh][wq * 16 + quad * 4 + r] = l_st[r];
    }
  }
  __syncthreads();

  // merge halves + gate + write Ab
  const int rr = tid >> 3, cg = (tid & 7) * 8;
  float m0 = Ml[0][rr], m1 = Ml[1][rr];
  float l0 = Ll[0][rr], l1 = Ll[1][rr];
  float m = fmaxf(m0, m1);
  float a0 = __expf(m0 - m), a1 = __expf(m1 - m);
  float inv = 1.f / (l0 * a0 + l1 * a1);
  float oc[8];
  #pragma unroll
  for (int cc = 0; cc < 8; ++cc)
    oc[cc] = (Om[0][rr][cg + cc] * a0 + Om[1][rr][cg + cc] * a1) * inv;
  size_t bt = (size_t)b * T_ + q0 + rr;
  #pragma unroll
  for (int e = 0; e < E_; ++e) {
    float g = sdg[bt * 40 + h * E_ + e];
    union { u16 s[8]; uint4 v; } o;
    #pragma unroll
    for (int cc = 0; cc < 8; ++cc) o.s[cc] = f2bf(g * oc[cc]);
    *(uint4*)(Ab + bt * KOUT + (h * E_ + e) * 64 + cg) = o.v;
  }
}

// ---------------- launch ----------------

extern "C" void kernel_launch(void* const* d_in, const int* in_sizes, int n_in,
                              void* d_out, int out_size, void* d_ws, size_t ws_size,
                              hipStream_t stream) {
  const float* x  = (const float*)d_in[0];
  const float* Wq = (const float*)d_in[1];
  const float* Wk = (const float*)d_in[2];
  const float* Wv = (const float*)d_in[3];
  const float* Ws = (const float*)d_in[4];
  const float* Wd = (const float*)d_in[5];
  const float* Wo = (const float*)d_in[6];
  float* out = (float*)d_out;

  char* ws = (char*)d_ws;
  u16*   WoT  = (u16*)(ws + 0);            //  5,242,880
  u16*   xb   = (u16*)(ws + 5242880);      //  4,194,304
  u16*   WT   = (u16*)(ws + 9437184);      //  7,340,032  (end 16,777,216)
  u16*   c1   = (u16*)(ws + 16777216);     // 14,680,064  (end 31,457,280)
  float* ssg  = (float*)(ws + 31457280);   //    327,680
  float* sdg  = (float*)(ws + 31784960);   //    327,680
  u16*   vT   = (u16*)(ws + 32112640);     //  2,097,152  (end 34,209,792)
  u16*   Ab   = (u16*)(ws + 34209792);     // 10,485,760  (end 44,695,552)
  u16*   Pk   = (u16*)(ws + 46137344);     // 16,777,216  (end 62,914,560)
  float* Pl   = (float*)(ws + 62914560);   //  5,242,880  (end 68,157,440)

  // routing: fp32 logits split-K GEMM (also emits xb bf16), then reduce+topk
  logits_kernel<<<dim3(32, 8), 256, 0, stream>>>(x, Ws, Wd, Pl, xb);
  topk_kernel<<<128, 256, 0, stream>>>(Pl, ssg, sdg);

  transpose_all_kernel<<<dim3(32, 112), 256, 0, stream>>>(Wq, Wk, Wv, WT);
  build_WoT_kernel<<<2560, 256, 0, stream>>>(Wo, WoT);

  // c1 = xb @ WT^T : M=2048, N=3584, K=1024
  gemm4w_kernel<1><<<dim3(16, 28, 1), 256, 0, stream>>>(xb, WT, c1, N1, 1024);

  vmix_tr_kernel<<<dim3(16, 32, 2), 256, 0, stream>>>(c1, ssg, vT);

  attn_kernel<<<dim3(32, 16), 256, 0, stream>>>(c1, vT, sdg, Ab);

  // out = Ab @ WoT^T : M=2048, N=1024, K=2560, split-K=4, bf16 partials
  gemm4w_kernel<4><<<dim3(16, 8, 4), 256, 0, stream>>>(Ab, WoT, Pk, 1024, KOUT);
  reduce4_kernel<<<1024, 256, 0, stream>>>(Pk, out);
}

// Round 5
// 186.940 us; speedup vs baseline: 1.2759x; 1.0297x over previous
//
#include <hip/hip_runtime.h>

typedef unsigned short u16;
typedef unsigned long long u64;
typedef __bf16 bf16x8 __attribute__((ext_vector_type(8)));
typedef float floatx4 __attribute__((ext_vector_type(4)));

#define B_   2
#define T_   1024
#define DIM_ 1024
#define H_   8
#define DH_  64
#define E_   5

// c1 column layout: [0,512) q | [512,1024) k | [1024,3584) vexp (h,e,dh)
#define N1   3584
#define M_   2048
#define KOUT 2560   // (h,e,c) contraction dim of output GEMM

__device__ __forceinline__ u16 f2bf(float f) {
  union { float f; unsigned u; } v; v.f = f;
  unsigned r = v.u + 0x7FFFu + ((v.u >> 16) & 1u);
  return (u16)(r >> 16);
}
__device__ __forceinline__ float bf2f(u16 h) {
  union { unsigned u; float f; } v; v.u = ((unsigned)h) << 16;
  return v.f;
}

__device__ __forceinline__ void async_cp16(const void* g, void* l) {
  __builtin_amdgcn_global_load_lds(
      (const __attribute__((address_space(1))) unsigned int*)g,
      (__attribute__((address_space(3))) unsigned int*)l, 16, 0, 0);
}

// ---------------- merged weight prep: WT (Wq|Wk|Wv transpose) + WoT gather ----------------

__global__ __launch_bounds__(256)
void prep_kernel(const float* __restrict__ Wq, const float* __restrict__ Wk,
                 const float* __restrict__ Wv, const float* __restrict__ Wo,
                 u16* __restrict__ WT, u16* __restrict__ WoT) {
  __shared__ float tile[32][33];
  if (blockIdx.y < 112) {
    int k0 = blockIdx.x * 32;
    int nt = blockIdx.y;
    const float* W; int N, n0, nofs;
    if (nt < 16)      { W = Wq; N = 512;  n0 = nt * 32;        nofs = 0; }
    else if (nt < 32) { W = Wk; N = 512;  n0 = (nt - 16) * 32; nofs = 512; }
    else              { W = Wv; N = 2560; n0 = (nt - 32) * 32; nofs = 1024; }
    int tx = threadIdx.x & 31, ty = threadIdx.x >> 5;
    #pragma unroll
    for (int i = 0; i < 32; i += 8)
      tile[ty + i][tx] = W[(size_t)(k0 + ty + i) * N + n0 + tx];
    __syncthreads();
    #pragma unroll
    for (int i = 0; i < 32; i += 8)
      WT[(size_t)(nofs + n0 + ty + i) * 1024 + k0 + tx] = f2bf(tile[tx][ty + i]);
  } else {
    int id = (blockIdx.y - 112) * 32 + blockIdx.x;   // 0..2559
    int i = id * 256 + threadIdx.x;                  // 655360 groups of 4
    int c4 = i & 15;
    int t  = i >> 4;
    int d  = t / 40;
    int he = t - d * 40;
    float4 v = *(const float4*)(Wo + ((size_t)(he * 1024 + d) * 64 + c4 * 4));
    union { u16 s[4]; uint2 u; } o;
    o.s[0] = f2bf(v.x); o.s[1] = f2bf(v.y); o.s[2] = f2bf(v.z); o.s[3] = f2bf(v.w);
    *(uint2*)(WoT + (size_t)d * KOUT + he * 64 + c4 * 4) = o.u;
  }
}

// ---------------- fp32 logits GEMM (split-K=8) + fused x->bf16 emit ----------------

__global__ __launch_bounds__(256)
void logits_kernel(const float* __restrict__ x, const float* __restrict__ Ws,
                   const float* __restrict__ Wd, float* __restrict__ Pl,
                   u16* __restrict__ xb) {
  __shared__ float xs[16][68];
  __shared__ float wt[16][80];
  const int tid = threadIdx.x;
  const int m0 = blockIdx.x * 64;
  const int kbeg = blockIdx.y * 128;
  const int tx = tid & 15, ty = tid >> 4;
  const int srow = tid >> 2, skq = tid & 3;

  float acc[4][5];
  #pragma unroll
  for (int r = 0; r < 4; ++r)
    #pragma unroll
    for (int c = 0; c < 5; ++c) acc[r][c] = 0.f;

  for (int s = 0; s < 8; ++s) {
    const int k0 = kbeg + s * 16;
    __syncthreads();
    {
      float4 v = *(const float4*)(x + (size_t)(m0 + srow) * 1024 + k0 + skq * 4);
      xs[skq * 4 + 0][srow] = v.x; xs[skq * 4 + 1][srow] = v.y;
      xs[skq * 4 + 2][srow] = v.z; xs[skq * 4 + 3][srow] = v.w;
      union { u16 h[4]; uint2 u; } o;
      o.h[0] = f2bf(v.x); o.h[1] = f2bf(v.y); o.h[2] = f2bf(v.z); o.h[3] = f2bf(v.w);
      *(uint2*)(xb + (size_t)(m0 + srow) * 1024 + k0 + skq * 4) = o.u;
    }
    #pragma unroll
    for (int j = 0; j < 5; ++j) {
      int f = j * 256 + tid;
      int kk = f / 80, c = f - kk * 80;
      wt[kk][c] = (c < 40) ? Ws[(size_t)(k0 + kk) * 40 + c]
                           : Wd[(size_t)(k0 + kk) * 40 + c - 40];
    }
    __syncthreads();

    #pragma unroll
    for (int kk = 0; kk < 16; ++kk) {
      float4 xv = *(const float4*)(&xs[kk][ty * 4]);
      float xr[4] = {xv.x, xv.y, xv.z, xv.w};
      #pragma unroll
      for (int c = 0; c < 5; ++c) {
        float wv = wt[kk][tx * 5 + c];
        #pragma unroll
        for (int r = 0; r < 4; ++r) acc[r][c] = fmaf(xr[r], wv, acc[r][c]);
      }
    }
  }

  float* P = Pl + (size_t)blockIdx.y * M_ * 80;
  #pragma unroll
  for (int r = 0; r < 4; ++r)
    #pragma unroll
    for (int c = 0; c < 5; ++c)
      P[(size_t)(m0 + ty * 4 + r) * 80 + tx * 5 + c] = acc[r][c];
}

// reduce 8 partials + sigmoid + top-k -> ssg (soft gates), sdb (40-bit mask per bt)
__global__ __launch_bounds__(256)
void topk_kernel(const float* __restrict__ Pl, float* __restrict__ ssg,
                 u64* __restrict__ sdb) {
  __shared__ float lg[16][80];
  __shared__ unsigned char mb[16][8];
  const int bt0 = blockIdx.x * 16;
  const int tid = threadIdx.x;
  #pragma unroll
  for (int j = 0; j < 5; ++j) {
    int f = j * 256 + tid;
    int r = f / 80, c = f - r * 80;
    float s = 0.f;
    #pragma unroll
    for (int z = 0; z < 8; ++z)
      s += Pl[(size_t)z * M_ * 80 + (size_t)(bt0 + r) * 80 + c];
    lg[r][c] = s;
  }
  __syncthreads();

  const int r = tid >> 4, h = (tid >> 1) & 7, side = tid & 1;
  float z[E_], g[E_]; bool sel[E_];
  #pragma unroll
  for (int e = 0; e < E_; ++e) {
    z[e] = lg[r][side * 40 + h * E_ + e];
    g[e] = 1.f / (1.f + __expf(-z[e]));
    sel[e] = false;
  }
  #pragma unroll
  for (int it = 0; it < 3; ++it) {
    int bi = 0; float bv = -3e38f;
    #pragma unroll
    for (int e = 0; e < E_; ++e)
      if (!sel[e] && z[e] > bv) { bv = z[e]; bi = e; }
    sel[bi] = true;
  }
  if (side == 0) {
    #pragma unroll
    for (int e = 0; e < E_; ++e)
      ssg[(size_t)(bt0 + r) * 40 + h * E_ + e] = sel[e] ? g[e] : 0.f;
  } else {
    unsigned bits = 0;
    #pragma unroll
    for (int e = 0; e < E_; ++e) bits |= (sel[e] ? 1u : 0u) << e;
    mb[r][h] = (unsigned char)bits;
  }
  __syncthreads();
  if (tid < 16) {
    u64 m = 0;
    #pragma unroll
    for (int hh = 0; hh < 8; ++hh) m |= (u64)mb[tid][hh] << (5 * hh);
    sdb[bt0 + tid] = m;
  }
}

// ---------------- m97-style MFMA GEMM, 128x128 tile, swizzled LDS, C = A @ B^T ----------------

__global__ __launch_bounds__(256)
void gemm4w_kernel(const u16* __restrict__ A, const u16* __restrict__ Bm,
                   u16* __restrict__ C, int N, int Kd) {
  constexpr int BK = 32;
  __shared__ __align__(16) u16 As[128 * BK];
  __shared__ __align__(16) u16 Bs[128 * BK];
  const int tid = threadIdx.x;
  const int w = tid >> 6, lane = tid & 63;
  const int ln15 = lane & 15, quad = lane >> 4;
  const int wm = w >> 1, wn = w & 1;
  const int bm0 = blockIdx.x * 128, bn0 = blockIdx.y * 128;
  const int lrow = lane >> 2;
  const int lg8 = (((lane & 3) ^ ((lane >> 3) & 3))) * 8;
  const int swz = (ln15 >> 1) & 3;

  floatx4 acc[4][4];
  #pragma unroll
  for (int i = 0; i < 4; ++i)
    #pragma unroll
    for (int j = 0; j < 4; ++j) acc[i][j] = (floatx4){0.f, 0.f, 0.f, 0.f};

  for (int k0 = 0; k0 < Kd; k0 += BK) {
    __syncthreads();
    #pragma unroll
    for (int j = 0; j < 2; ++j) {
      int i = w * 2 + j;
      async_cp16(A + (size_t)(bm0 + i * 16 + lrow) * Kd + k0 + lg8, (char*)As + i * 1024);
      async_cp16(Bm + (size_t)(bn0 + i * 16 + lrow) * Kd + k0 + lg8, (char*)Bs + i * 1024);
    }
    __builtin_amdgcn_s_waitcnt(0);
    __syncthreads();

    bf16x8 af[4], bf[4];
    #pragma unroll
    for (int mt = 0; mt < 4; ++mt)
      af[mt] = *(const bf16x8*)(As + (wm * 64 + mt * 16 + ln15) * BK + ((quad ^ swz) * 8));
    #pragma unroll
    for (int nt = 0; nt < 4; ++nt)
      bf[nt] = *(const bf16x8*)(Bs + (wn * 64 + nt * 16 + ln15) * BK + ((quad ^ swz) * 8));
    #pragma unroll
    for (int mt = 0; mt < 4; ++mt)
      #pragma unroll
      for (int nt = 0; nt < 4; ++nt)
        acc[mt][nt] = __builtin_amdgcn_mfma_f32_16x16x32_bf16(af[mt], bf[nt], acc[mt][nt], 0, 0, 0);
  }

  #pragma unroll
  for (int mt = 0; mt < 4; ++mt)
    #pragma unroll
    for (int nt = 0; nt < 4; ++nt)
      #pragma unroll
      for (int r = 0; r < 4; ++r) {
        int m = bm0 + wm * 64 + mt * 16 + quad * 4 + r;
        int n = bn0 + wn * 64 + nt * 16 + ln15;
        C[(size_t)m * N + n] = f2bf(acc[mt][nt][r]);
      }
}

// ---------------- GEMM2 fused: A[m=bt][k=he*64+c] = (sdb[bt]>>he & 1) ? o_bh[b,h,t,c] : 0 ----------------
// C = A @ WoT^T, split-K=4 bf16 partials. N=1024, K=2560.

__global__ __launch_bounds__(256)
void gemm2f_kernel(const u16* __restrict__ o_bh, const u16* __restrict__ WoT,
                   const u64* __restrict__ sdb, u16* __restrict__ Pk) {
  constexpr int BK = 32, Kd = KOUT;
  __shared__ __align__(16) u16 As[128 * BK];
  __shared__ __align__(16) u16 Bs[128 * BK];
  const int tid = threadIdx.x;
  const int w = tid >> 6, lane = tid & 63;
  const int ln15 = lane & 15, quad = lane >> 4;
  const int wm = w >> 1, wn = w & 1;
  const int bm0 = blockIdx.x * 128, bn0 = blockIdx.y * 128;
  const int b = bm0 >> 10;                         // batch (uniform per block)
  const int t_base = bm0 & 1023;
  const int lrow = lane >> 2;
  const int lg8 = (((lane & 3) ^ ((lane >> 3) & 3))) * 8;
  const int swz = (ln15 >> 1) & 3;
  const int kbeg = blockIdx.z * 640;

  u64 sdr[4];
  #pragma unroll
  for (int mt = 0; mt < 4; ++mt)
    sdr[mt] = sdb[bm0 + wm * 64 + mt * 16 + ln15];

  floatx4 acc[4][4];
  #pragma unroll
  for (int i = 0; i < 4; ++i)
    #pragma unroll
    for (int j = 0; j < 4; ++j) acc[i][j] = (floatx4){0.f, 0.f, 0.f, 0.f};

  for (int k0 = kbeg; k0 < kbeg + 640; k0 += BK) {
    const int he = k0 >> 6;                        // 0..39 (uniform)
    const int h = (he * 205) >> 10;                // he / 5
    const int c0 = k0 & 63;                        // 0 or 32
    const u16* abase = o_bh + ((size_t)((b * 8 + h) * 1024 + t_base) * 64) + c0;
    __syncthreads();
    #pragma unroll
    for (int j = 0; j < 2; ++j) {
      int i = w * 2 + j;
      async_cp16(abase + (size_t)(i * 16 + lrow) * 64 + lg8, (char*)As + i * 1024);
      async_cp16(WoT + (size_t)(bn0 + i * 16 + lrow) * Kd + k0 + lg8, (char*)Bs + i * 1024);
    }
    __builtin_amdgcn_s_waitcnt(0);
    __syncthreads();

    bf16x8 af[4], bf[4];
    union { uint4 u; bf16x8 v; } z8; z8.u = (uint4){0u, 0u, 0u, 0u};
    #pragma unroll
    for (int mt = 0; mt < 4; ++mt) {
      af[mt] = *(const bf16x8*)(As + (wm * 64 + mt * 16 + ln15) * BK + ((quad ^ swz) * 8));
      if (!((sdr[mt] >> he) & 1)) af[mt] = z8.v;   // sd gate: 0/1 select
    }
    #pragma unroll
    for (int nt = 0; nt < 4; ++nt)
      bf[nt] = *(const bf16x8*)(Bs + (wn * 64 + nt * 16 + ln15) * BK + ((quad ^ swz) * 8));
    #pragma unroll
    for (int mt = 0; mt < 4; ++mt)
      #pragma unroll
      for (int nt = 0; nt < 4; ++nt)
        acc[mt][nt] = __builtin_amdgcn_mfma_f32_16x16x32_bf16(af[mt], bf[nt], acc[mt][nt], 0, 0, 0);
  }

  u16* Cz = Pk + (size_t)blockIdx.z * M_ * 1024;
  #pragma unroll
  for (int mt = 0; mt < 4; ++mt)
    #pragma unroll
    for (int nt = 0; nt < 4; ++nt)
      #pragma unroll
      for (int r = 0; r < 4; ++r) {
        int m = bm0 + wm * 64 + mt * 16 + quad * 4 + r;
        int n = bn0 + wn * 64 + nt * 16 + ln15;
        Cz[(size_t)m * 1024 + n] = f2bf(acc[mt][nt][r]);
      }
}

// reduce 4 bf16 split-K partials -> fp32 out
__global__ void reduce4_kernel(const u16* __restrict__ Pk, float* __restrict__ out) {
  int i = blockIdx.x * 256 + threadIdx.x;
  size_t base = (size_t)i * 8;
  float s[8] = {0.f, 0.f, 0.f, 0.f, 0.f, 0.f, 0.f, 0.f};
  #pragma unroll
  for (int z = 0; z < 4; ++z) {
    union { uint4 v; u16 h[8]; } u;
    u.v = *(const uint4*)(Pk + (size_t)z * M_ * 1024 + base);
    #pragma unroll
    for (int c = 0; c < 8; ++c) s[c] += bf2f(u.h[c]);
  }
  float4 o0 = {s[0], s[1], s[2], s[3]}, o1 = {s[4], s[5], s[6], s[7]};
  *(float4*)(out + base) = o0;
  *(float4*)(out + base + 4) = o1;
}

// ---------------- fused V-mix + transpose: vexp,ssg -> vT[(b,h,dh)][t] ----------------

__global__ __launch_bounds__(256)
void vmix_tr_kernel(const u16* __restrict__ c1, const float* __restrict__ ssg,
                    u16* __restrict__ vT) {
  __shared__ u16 tile[32][33];
  const int bh = blockIdx.x;
  const int b = bh >> 3, h = bh & 7;
  const int t0 = blockIdx.y * 32, d0 = blockIdx.z * 32;
  const int dh = threadIdx.x & 31, tl = threadIdx.x >> 5;
  #pragma unroll
  for (int i = 0; i < 4; ++i) {
    int trow = tl + i * 8;
    size_t bt = (size_t)b * T_ + t0 + trow;
    const u16* ve = c1 + bt * N1 + 1024 + h * (E_ * 64) + d0 + dh;
    const float* g = ssg + bt * 40 + h * E_;
    float s = 0.f;
    #pragma unroll
    for (int e = 0; e < E_; ++e) s = fmaf(g[e], bf2f(ve[e * 64]), s);
    tile[trow][dh] = f2bf(s);
  }
  __syncthreads();
  #pragma unroll
  for (int i = 0; i < 4; ++i) {
    int d = d0 + tl + i * 8;
    vT[((size_t)(b * H_ + h) * DH_ + d) * T_ + t0 + dh] = tile[dh][tl + i * 8];
  }
}

// ---------------- flash attention: balanced 32-row Q tiles, wave-pairs split kt ----------------

__global__ __launch_bounds__(256)
void attn_kernel(const u16* __restrict__ c1, const u16* __restrict__ vT,
                 u16* __restrict__ o_bh) {
  __shared__ __align__(16) u16 Qs[32 * 64];
  __shared__ __align__(16) u16 Ks[2][64 * 64];
  __shared__ __align__(16) u16 Vs[2][64 * 64];
  __shared__ __align__(16) u16 Ps[2][32 * 72];
  __shared__ float Om[2][32][68];
  __shared__ float Ml[2][32], Ll[2][32];
  const int bx = blockIdx.x;
  const int qi = (bx & 1) ? (bx >> 1) : (31 - (bx >> 1));   // heavy/light interleave
  const int bh = blockIdx.y;
  const int b = bh >> 3, h = bh & 7;
  const int tid = threadIdx.x;
  const int w = tid >> 6, lane = tid & 63;
  const int ln15 = lane & 15, quad = lane >> 4;
  const int hh = w >> 1, wq = w & 1;
  const int q0 = qi * 32;
  const int nkt = (qi >> 1) + 1;
  const int h0n = (nkt + 1) >> 1;
  const int r8 = lane >> 3;
  const int g8 = ((lane & 7) ^ ((lane >> 3) & 7)) * 8;
  const int swz = ln15 & 7;

  async_cp16(c1 + (size_t)(b * T_ + q0 + w * 8 + r8) * N1 + h * DH_ + g8,
             (char*)Qs + w * 1024);

  floatx4 O[4];
  float m_st[4], l_st[4];
  #pragma unroll
  for (int j = 0; j < 4; ++j) {
    O[j] = (floatx4){0.f, 0.f, 0.f, 0.f};
    m_st[j] = -3e38f; l_st[j] = 0.f;
  }
  const int qrow = q0 + wq * 16 + quad * 4;

  for (int j = 0; j < h0n; ++j) {
    const int myt = hh ? (h0n + j) : j;
    const bool act = (hh == 0) || (h0n + j < nkt);
    __syncthreads();
    if (w < 2 || h0n + j < nkt) {
      const int tk = (w < 2 ? j : h0n + j) * 64;
      if ((w & 1) == 0) {
        #pragma unroll
        for (int i = 0; i < 8; ++i)
          async_cp16(c1 + (size_t)(b * T_ + tk + i * 8 + r8) * N1 + 512 + h * DH_ + g8,
                     (char*)Ks[w >> 1] + i * 1024);
      } else {
        #pragma unroll
        for (int i = 0; i < 8; ++i)
          async_cp16(vT + (size_t)((b * H_ + h) * DH_ + i * 8 + r8) * T_ + tk + g8,
                     (char*)Vs[w >> 1] + i * 1024);
      }
    }
    __builtin_amdgcn_s_waitcnt(0);
    __syncthreads();

    float p[4][4];
    if (act) {
      const int tk0 = myt * 64;
      floatx4 S[4];
      #pragma unroll
      for (int nt = 0; nt < 4; ++nt) S[nt] = (floatx4){0.f, 0.f, 0.f, 0.f};
      #pragma unroll
      for (int ks = 0; ks < 2; ++ks) {
        bf16x8 a = *(const bf16x8*)(Qs + (wq * 16 + ln15) * 64 + (((ks * 4 + quad) ^ swz)) * 8);
        #pragma unroll
        for (int nt = 0; nt < 4; ++nt) {
          bf16x8 bv = *(const bf16x8*)(&Ks[hh][(nt * 16 + ln15) * 64 + (((ks * 4 + quad) ^ swz)) * 8]);
          S[nt] = __builtin_amdgcn_mfma_f32_16x16x32_bf16(a, bv, S[nt], 0, 0, 0);
        }
      }
      float rmax[4], alpha[4], rsum[4];
      #pragma unroll
      for (int r = 0; r < 4; ++r) rmax[r] = -3e38f;
      #pragma unroll
      for (int nt = 0; nt < 4; ++nt) {
        int col = tk0 + nt * 16 + ln15;
        #pragma unroll
        for (int r = 0; r < 4; ++r) {
          float s = S[nt][r] * 0.125f;
          if (col > qrow + r) s = -3e38f;
          p[nt][r] = s;
          rmax[r] = fmaxf(rmax[r], s);
        }
      }
      #pragma unroll
      for (int r = 0; r < 4; ++r) {
        #pragma unroll
        for (int off = 1; off < 16; off <<= 1)
          rmax[r] = fmaxf(rmax[r], __shfl_xor(rmax[r], off));
        float mn = fmaxf(m_st[r], rmax[r]);
        alpha[r] = __expf(m_st[r] - mn);
        m_st[r] = mn;
        rsum[r] = 0.f;
      }
      #pragma unroll
      for (int nt = 0; nt < 4; ++nt)
        #pragma unroll
        for (int r = 0; r < 4; ++r) {
          float e = __expf(p[nt][r] - m_st[r]);
          p[nt][r] = e;
          rsum[r] += e;
        }
      #pragma unroll
      for (int r = 0; r < 4; ++r) {
        #pragma unroll
        for (int off = 1; off < 16; off <<= 1)
          rsum[r] += __shfl_xor(rsum[r], off);
        l_st[r] = l_st[r] * alpha[r] + rsum[r];
      }
      #pragma unroll
      for (int nt = 0; nt < 4; ++nt)
        #pragma unroll
        for (int r = 0; r < 4; ++r) O[nt][r] *= alpha[r];
      #pragma unroll
      for (int nt = 0; nt < 4; ++nt)
        #pragma unroll
        for (int r = 0; r < 4; ++r)
          Ps[hh][(wq * 16 + quad * 4 + r) * 72 + nt * 16 + ln15] = f2bf(p[nt][r]);
    }
    __syncthreads();
    if (act) {
      #pragma unroll
      for (int ks = 0; ks < 2; ++ks) {
        bf16x8 a = *(const bf16x8*)(&Ps[hh][(wq * 16 + ln15) * 72 + ks * 32 + quad * 8]);
        #pragma unroll
        for (int nt = 0; nt < 4; ++nt) {
          bf16x8 bv = *(const bf16x8*)(&Vs[hh][(nt * 16 + ln15) * 64 + (((ks * 4 + quad) ^ swz)) * 8]);
          O[nt] = __builtin_amdgcn_mfma_f32_16x16x32_bf16(a, bv, O[nt], 0, 0, 0);
        }
      }
    }
  }

  #pragma unroll
  for (int nt = 0; nt < 4; ++nt)
    #pragma unroll
    for (int r = 0; r < 4; ++r)
      Om[hh][wq * 16 + quad * 4 + r][nt * 16 + ln15] = O[nt][r];
  if (ln15 == 0) {
    #pragma unroll
    for (int r = 0; r < 4; ++r) {
      Ml[hh][wq * 16 + quad * 4 + r] = m_st[r];
      Ll[hh][wq * 16 + quad * 4 + r] = l_st[r];
    }
  }
  __syncthreads();

  // merge halves + write compact o_bh
  const int rr = tid >> 3, cg = (tid & 7) * 8;
  float m0 = Ml[0][rr], m1 = Ml[1][rr];
  float l0 = Ll[0][rr], l1 = Ll[1][rr];
  float m = fmaxf(m0, m1);
  float a0 = __expf(m0 - m), a1 = __expf(m1 - m);
  float inv = 1.f / (l0 * a0 + l1 * a1);
  union { u16 s[8]; uint4 v; } o;
  #pragma unroll
  for (int cc = 0; cc < 8; ++cc)
    o.s[cc] = f2bf((Om[0][rr][cg + cc] * a0 + Om[1][rr][cg + cc] * a1) * inv);
  *(uint4*)(o_bh + ((size_t)((b * 8 + h) * 1024 + q0 + rr)) * 64 + cg) = o.v;
}

// ---------------- launch ----------------

extern "C" void kernel_launch(void* const* d_in, const int* in_sizes, int n_in,
                              void* d_out, int out_size, void* d_ws, size_t ws_size,
                              hipStream_t stream) {
  const float* x  = (const float*)d_in[0];
  const float* Wq = (const float*)d_in[1];
  const float* Wk = (const float*)d_in[2];
  const float* Wv = (const float*)d_in[3];
  const float* Ws = (const float*)d_in[4];
  const float* Wd = (const float*)d_in[5];
  const float* Wo = (const float*)d_in[6];
  float* out = (float*)d_out;

  char* ws = (char*)d_ws;
  u16*   WoT  = (u16*)(ws + 0);            //  5,242,880
  u16*   xb   = (u16*)(ws + 5242880);      //  4,194,304
  u16*   WT   = (u16*)(ws + 9437184);      //  7,340,032  (end 16,777,216)
  u16*   c1   = (u16*)(ws + 16777216);     // 14,680,064  (end 31,457,280)
  float* ssg  = (float*)(ws + 31457280);   //    327,680
  u64*   sdb  = (u64*)(ws + 31784960);     //     16,384
  u16*   o_bh = (u16*)(ws + 31801344);     //  2,097,152  (end 33,898,496)
  u16*   vT   = (u16*)(ws + 33898496);     //  2,097,152  (end 35,995,648)
  u16*   Pk   = (u16*)(ws + 35995648);     // 16,777,216  (end 52,772,864)
  float* Pl   = (float*)(ws + 52772864);   //  5,242,880  (end 58,015,744)

  logits_kernel<<<dim3(32, 8), 256, 0, stream>>>(x, Ws, Wd, Pl, xb);
  topk_kernel<<<128, 256, 0, stream>>>(Pl, ssg, sdb);

  prep_kernel<<<dim3(32, 192), 256, 0, stream>>>(Wq, Wk, Wv, Wo, WT, WoT);

  // c1 = xb @ WT^T : M=2048, N=3584, K=1024
  gemm4w_kernel<<<dim3(16, 28), 256, 0, stream>>>(xb, WT, c1, N1, 1024);

  vmix_tr_kernel<<<dim3(16, 32, 2), 256, 0, stream>>>(c1, ssg, vT);

  attn_kernel<<<dim3(32, 16), 256, 0, stream>>>(c1, vT, o_bh);

  // out = (sd ? o : 0) @ WoT^T : split-K=4, bf16 partials
  gemm2f_kernel<<<dim3(16, 8, 4), 256, 0, stream>>>(o_bh, WoT, sdb, Pk);
  reduce4_kernel<<<1024, 256, 0, stream>>>(Pk, out);
}

// Round 6
// 179.001 us; speedup vs baseline: 1.3325x; 1.0444x over previous
//
#include <hip/hip_runtime.h>

typedef unsigned short u16;
typedef unsigned long long u64;
typedef __bf16 bf16x8 __attribute__((ext_vector_type(8)));
typedef float floatx4 __attribute__((ext_vector_type(4)));

#define B_   2
#define T_   1024
#define DIM_ 1024
#define H_   8
#define DH_  64
#define E_   5

// c1 column layout: [0,512) q | [512,1024) k | [1024,3584) vexp (h,e,dh)
#define N1   3584
#define M_   2048
#define KOUT 2560

__device__ __forceinline__ u16 f2bf(float f) {
  union { float f; unsigned u; } v; v.f = f;
  unsigned r = v.u + 0x7FFFu + ((v.u >> 16) & 1u);
  return (u16)(r >> 16);
}
__device__ __forceinline__ float bf2f(u16 h) {
  union { unsigned u; float f; } v; v.u = ((unsigned)h) << 16;
  return v.f;
}

__device__ __forceinline__ void async_cp16(const void* g, void* l) {
  __builtin_amdgcn_global_load_lds(
      (const __attribute__((address_space(1))) unsigned int*)g,
      (__attribute__((address_space(3))) unsigned int*)l, 16, 0, 0);
}

// ---------------- preamble: [blocks 0..255] logits+topk (+xb emit) | [256..6399] weight prep ----------------
// xs index: pad 4 dwords every 64 k so the 16 k-slices land on distinct banks
#define XI(r, k) ((r) * 1088 + (k) + (((k) >> 6) << 2))

__global__ __launch_bounds__(256)
void preamble_kernel(const float* __restrict__ x, const float* __restrict__ Wq,
                     const float* __restrict__ Wk, const float* __restrict__ Wv,
                     const float* __restrict__ Ws, const float* __restrict__ Wd,
                     const float* __restrict__ Wo,
                     u16* __restrict__ WT, u16* __restrict__ WoT,
                     float* __restrict__ ssg, u64* __restrict__ sdb,
                     u16* __restrict__ xb) {
  __shared__ __align__(16) char smem[47744];
  const int bx = blockIdx.x;
  const int tid = threadIdx.x;

  if (bx >= 256) {                    // ---- weight prep ----
    const int pb = bx - 256;
    const int kx = pb & 31, nt = pb >> 5;
    if (nt < 112) {
      float (*tile)[33] = (float(*)[33])smem;
      int k0 = kx * 32;
      const float* W; int N, n0, nofs;
      if (nt < 16)      { W = Wq; N = 512;  n0 = nt * 32;        nofs = 0; }
      else if (nt < 32) { W = Wk; N = 512;  n0 = (nt - 16) * 32; nofs = 512; }
      else              { W = Wv; N = 2560; n0 = (nt - 32) * 32; nofs = 1024; }
      int tx = tid & 31, ty = tid >> 5;
      #pragma unroll
      for (int i = 0; i < 32; i += 8)
        tile[ty + i][tx] = W[(size_t)(k0 + ty + i) * N + n0 + tx];
      __syncthreads();
      #pragma unroll
      for (int i = 0; i < 32; i += 8)
        WT[(size_t)(nofs + n0 + ty + i) * 1024 + k0 + tx] = f2bf(tile[tx][ty + i]);
    } else {
      int id = (nt - 112) * 32 + kx;               // 0..2559
      int i = id * 256 + tid;
      int c4 = i & 15;
      int t  = i >> 4;
      int d  = t / 40;
      int he = t - d * 40;
      float4 v = *(const float4*)(Wo + ((size_t)(he * 1024 + d) * 64 + c4 * 4));
      union { u16 s[4]; uint2 u; } o;
      o.s[0] = f2bf(v.x); o.s[1] = f2bf(v.y); o.s[2] = f2bf(v.z); o.s[3] = f2bf(v.w);
      *(uint2*)(WoT + (size_t)d * KOUT + he * 64 + c4 * 4) = o.u;
    }
    return;
  }

  // ---- logits + topk, rows bt0..bt0+7 ----
  float* xs = (float*)smem;                         // [8][1088]  34816 B
  float* ps = xs + 8 * 1088;                        // [4][8][80] 10240 B
  float* lg = ps + 4 * 640;                         // [8][80]     2560 B
  unsigned char* mb = (unsigned char*)(lg + 640);   // [8][8]
  const int bt0 = bx * 8;

  for (int i = tid; i < 2048; i += 256) {           // stage x + emit xb
    int r = i >> 8, j = i & 255;
    float4 v = ((const float4*)(x + (size_t)(bt0 + r) * 1024))[j];
    *(float4*)(xs + XI(r, j * 4)) = v;
    union { u16 h[4]; uint2 u; } o;
    o.h[0] = f2bf(v.x); o.h[1] = f2bf(v.y); o.h[2] = f2bf(v.z); o.h[3] = f2bf(v.w);
    *(uint2*)(xb + (size_t)(bt0 + r) * 1024 + j * 4) = o.u;
  }
  __syncthreads();

  const int cx = tid & 15;                          // 5 cols each
  const int ky = tid >> 4;                          // 16 k-slices of 64
  float acc[8][5];
  #pragma unroll
  for (int r = 0; r < 8; ++r)
    #pragma unroll
    for (int c = 0; c < 5; ++c) acc[r][c] = 0.f;

  for (int q4 = 0; q4 < 16; ++q4) {
    const int k = ky * 64 + q4 * 4;
    float4 xr[8];
    #pragma unroll
    for (int r = 0; r < 8; ++r) xr[r] = *(const float4*)(xs + XI(r, k));
    #pragma unroll
    for (int c = 0; c < 5; ++c) {
      const int col = cx * 5 + c;
      const float* Wp = (col < 40) ? (Ws + col) : (Wd + col - 40);
      float w0 = Wp[(size_t)(k + 0) * 40], w1 = Wp[(size_t)(k + 1) * 40];
      float w2 = Wp[(size_t)(k + 2) * 40], w3 = Wp[(size_t)(k + 3) * 40];
      #pragma unroll
      for (int r = 0; r < 8; ++r) {
        float a = acc[r][c];
        a = fmaf(xr[r].x, w0, a); a = fmaf(xr[r].y, w1, a);
        a = fmaf(xr[r].z, w2, a); a = fmaf(xr[r].w, w3, a);
        acc[r][c] = a;
      }
    }
  }

  // reduce ky within wave (lanes ^16, ^32), then across 4 waves via LDS
  #pragma unroll
  for (int r = 0; r < 8; ++r)
    #pragma unroll
    for (int c = 0; c < 5; ++c) {
      float a = acc[r][c];
      a += __shfl_xor(a, 16);
      a += __shfl_xor(a, 32);
      acc[r][c] = a;
    }
  const int w = tid >> 6, lane = tid & 63;
  if (lane < 16) {
    #pragma unroll
    for (int r = 0; r < 8; ++r)
      #pragma unroll
      for (int c = 0; c < 5; ++c)
        ps[w * 640 + r * 80 + lane * 5 + c] = acc[r][c];
  }
  __syncthreads();
  for (int idx = tid; idx < 640; idx += 256)
    lg[idx] = ps[idx] + ps[640 + idx] + ps[1280 + idx] + ps[1920 + idx];
  __syncthreads();

  if (tid < 128) {
    const int r = tid >> 4, h = (tid >> 1) & 7, side = tid & 1;
    float z[E_], g[E_]; bool sel[E_];
    #pragma unroll
    for (int e = 0; e < E_; ++e) {
      z[e] = lg[r * 80 + side * 40 + h * E_ + e];
      g[e] = 1.f / (1.f + __expf(-z[e]));
      sel[e] = false;
    }
    #pragma unroll
    for (int it = 0; it < 3; ++it) {
      int bi = 0; float bv = -3e38f;
      #pragma unroll
      for (int e = 0; e < E_; ++e)
        if (!sel[e] && z[e] > bv) { bv = z[e]; bi = e; }
      sel[bi] = true;
    }
    if (side == 0) {
      #pragma unroll
      for (int e = 0; e < E_; ++e)
        ssg[(size_t)(bt0 + r) * 40 + h * E_ + e] = sel[e] ? g[e] : 0.f;
    } else {
      unsigned bits = 0;
      #pragma unroll
      for (int e = 0; e < E_; ++e) bits |= (sel[e] ? 1u : 0u) << e;
      mb[r * 8 + h] = (unsigned char)bits;
    }
  }
  __syncthreads();
  if (tid < 8) {
    u64 m = 0;
    #pragma unroll
    for (int hh = 0; hh < 8; ++hh) m |= (u64)mb[tid * 8 + hh] << (5 * hh);
    sdb[bt0 + tid] = m;
  }
}

// ---------------- MFMA GEMM, 128x128 tile, BK=64, swizzled LDS, C = A @ B^T ----------------

__global__ __launch_bounds__(256, 2)
void gemm4w_kernel(const u16* __restrict__ A, const u16* __restrict__ Bm,
                   u16* __restrict__ C, int N, int Kd) {
  __shared__ __align__(16) u16 As[128 * 64];   // 16 KB
  __shared__ __align__(16) u16 Bs[128 * 64];   // 16 KB
  const int tid = threadIdx.x;
  const int w = tid >> 6, lane = tid & 63;
  const int ln15 = lane & 15, quad = lane >> 4;
  const int wm = w >> 1, wn = w & 1;
  const int bm0 = blockIdx.x * 128, bn0 = blockIdx.y * 128;
  const int r8 = lane >> 3;
  const int g8 = ((lane & 7) ^ r8) * 8;        // swizzled src chunk
  const int swz = ln15 & 7;

  floatx4 acc[4][4];
  #pragma unroll
  for (int i = 0; i < 4; ++i)
    #pragma unroll
    for (int j = 0; j < 4; ++j) acc[i][j] = (floatx4){0.f, 0.f, 0.f, 0.f};

  for (int k0 = 0; k0 < Kd; k0 += 64) {
    __syncthreads();
    #pragma unroll
    for (int j = 0; j < 4; ++j) {
      int i = w * 4 + j;                        // 8-row groups
      async_cp16(A + (size_t)(bm0 + i * 8 + r8) * Kd + k0 + g8, (char*)As + i * 1024);
      async_cp16(Bm + (size_t)(bn0 + i * 8 + r8) * Kd + k0 + g8, (char*)Bs + i * 1024);
    }
    __builtin_amdgcn_s_waitcnt(0);
    __syncthreads();

    #pragma unroll
    for (int t = 0; t < 2; ++t) {
      bf16x8 af[4], bf[4];
      #pragma unroll
      for (int mt = 0; mt < 4; ++mt)
        af[mt] = *(const bf16x8*)(As + (wm * 64 + mt * 16 + ln15) * 64 + (((t * 4 + quad) ^ swz) * 8));
      #pragma unroll
      for (int nt = 0; nt < 4; ++nt)
        bf[nt] = *(const bf16x8*)(Bs + (wn * 64 + nt * 16 + ln15) * 64 + (((t * 4 + quad) ^ swz) * 8));
      #pragma unroll
      for (int mt = 0; mt < 4; ++mt)
        #pragma unroll
        for (int nt = 0; nt < 4; ++nt)
          acc[mt][nt] = __builtin_amdgcn_mfma_f32_16x16x32_bf16(af[mt], bf[nt], acc[mt][nt], 0, 0, 0);
    }
  }

  #pragma unroll
  for (int mt = 0; mt < 4; ++mt)
    #pragma unroll
    for (int nt = 0; nt < 4; ++nt)
      #pragma unroll
      for (int r = 0; r < 4; ++r) {
        int m = bm0 + wm * 64 + mt * 16 + quad * 4 + r;
        int n = bn0 + wn * 64 + nt * 16 + ln15;
        C[(size_t)m * N + n] = f2bf(acc[mt][nt][r]);
      }
}

// ---------------- GEMM2 fused: A[bt][he*64+c] = (sdb>>he&1) ? o_bh[b,h,t,c] : 0 ----------------

__global__ __launch_bounds__(256, 2)
void gemm2f_kernel(const u16* __restrict__ o_bh, const u16* __restrict__ WoT,
                   const u64* __restrict__ sdb, u16* __restrict__ Pk) {
  __shared__ __align__(16) u16 As[128 * 64];
  __shared__ __align__(16) u16 Bs[128 * 64];
  const int tid = threadIdx.x;
  const int w = tid >> 6, lane = tid & 63;
  const int ln15 = lane & 15, quad = lane >> 4;
  const int wm = w >> 1, wn = w & 1;
  const int bm0 = blockIdx.x * 128, bn0 = blockIdx.y * 128;
  const int b = bm0 >> 10;
  const int t_base = bm0 & 1023;
  const int r8 = lane >> 3;
  const int g8 = ((lane & 7) ^ r8) * 8;
  const int swz = ln15 & 7;
  const int kbeg = blockIdx.z * 640;

  u64 sdr[4];
  #pragma unroll
  for (int mt = 0; mt < 4; ++mt)
    sdr[mt] = sdb[bm0 + wm * 64 + mt * 16 + ln15];

  floatx4 acc[4][4];
  #pragma unroll
  for (int i = 0; i < 4; ++i)
    #pragma unroll
    for (int j = 0; j < 4; ++j) acc[i][j] = (floatx4){0.f, 0.f, 0.f, 0.f};

  for (int k0 = kbeg; k0 < kbeg + 640; k0 += 64) {
    const int he = k0 >> 6;                      // one head-channel block per iter
    const int h = (he * 205) >> 10;              // he / 5
    const u16* abase = o_bh + (size_t)((b * 8 + h) * 1024 + t_base) * 64;
    __syncthreads();
    #pragma unroll
    for (int j = 0; j < 4; ++j) {
      int i = w * 4 + j;
      async_cp16(abase + (size_t)(i * 8 + r8) * 64 + g8, (char*)As + i * 1024);
      async_cp16(WoT + (size_t)(bn0 + i * 8 + r8) * KOUT + k0 + g8, (char*)Bs + i * 1024);
    }
    __builtin_amdgcn_s_waitcnt(0);
    __syncthreads();

    union { uint4 u; bf16x8 v; } z8; z8.u = (uint4){0u, 0u, 0u, 0u};
    #pragma unroll
    for (int t = 0; t < 2; ++t) {
      bf16x8 af[4], bf[4];
      #pragma unroll
      for (int mt = 0; mt < 4; ++mt) {
        af[mt] = *(const bf16x8*)(As + (wm * 64 + mt * 16 + ln15) * 64 + (((t * 4 + quad) ^ swz) * 8));
        if (!((sdr[mt] >> he) & 1)) af[mt] = z8.v;
      }
      #pragma unroll
      for (int nt = 0; nt < 4; ++nt)
        bf[nt] = *(const bf16x8*)(Bs + (wn * 64 + nt * 16 + ln15) * 64 + (((t * 4 + quad) ^ swz) * 8));
      #pragma unroll
      for (int mt = 0; mt < 4; ++mt)
        #pragma unroll
        for (int nt = 0; nt < 4; ++nt)
          acc[mt][nt] = __builtin_amdgcn_mfma_f32_16x16x32_bf16(af[mt], bf[nt], acc[mt][nt], 0, 0, 0);
    }
  }

  u16* Cz = Pk + (size_t)blockIdx.z * M_ * 1024;
  #pragma unroll
  for (int mt = 0; mt < 4; ++mt)
    #pragma unroll
    for (int nt = 0; nt < 4; ++nt)
      #pragma unroll
      for (int r = 0; r < 4; ++r) {
        int m = bm0 + wm * 64 + mt * 16 + quad * 4 + r;
        int n = bn0 + wn * 64 + nt * 16 + ln15;
        Cz[(size_t)m * 1024 + n] = f2bf(acc[mt][nt][r]);
      }
}

// reduce 4 bf16 split-K partials -> fp32 out
__global__ void reduce4_kernel(const u16* __restrict__ Pk, float* __restrict__ out) {
  int i = blockIdx.x * 256 + threadIdx.x;
  size_t base = (size_t)i * 8;
  float s[8] = {0.f, 0.f, 0.f, 0.f, 0.f, 0.f, 0.f, 0.f};
  #pragma unroll
  for (int z = 0; z < 4; ++z) {
    union { uint4 v; u16 h[8]; } u;
    u.v = *(const uint4*)(Pk + (size_t)z * M_ * 1024 + base);
    #pragma unroll
    for (int c = 0; c < 8; ++c) s[c] += bf2f(u.h[c]);
  }
  float4 o0 = {s[0], s[1], s[2], s[3]}, o1 = {s[4], s[5], s[6], s[7]};
  *(float4*)(out + base) = o0;
  *(float4*)(out + base + 4) = o1;
}

// ---------------- fused V-mix + transpose ----------------

__global__ __launch_bounds__(256)
void vmix_tr_kernel(const u16* __restrict__ c1, const float* __restrict__ ssg,
                    u16* __restrict__ vT) {
  __shared__ u16 tile[32][33];
  const int bh = blockIdx.x;
  const int b = bh >> 3, h = bh & 7;
  const int t0 = blockIdx.y * 32, d0 = blockIdx.z * 32;
  const int dh = threadIdx.x & 31, tl = threadIdx.x >> 5;
  #pragma unroll
  for (int i = 0; i < 4; ++i) {
    int trow = tl + i * 8;
    size_t bt = (size_t)b * T_ + t0 + trow;
    const u16* ve = c1 + bt * N1 + 1024 + h * (E_ * 64) + d0 + dh;
    const float* g = ssg + bt * 40 + h * E_;
    float s = 0.f;
    #pragma unroll
    for (int e = 0; e < E_; ++e) s = fmaf(g[e], bf2f(ve[e * 64]), s);
    tile[trow][dh] = f2bf(s);
  }
  __syncthreads();
  #pragma unroll
  for (int i = 0; i < 4; ++i) {
    int d = d0 + tl + i * 8;
    vT[((size_t)(b * H_ + h) * DH_ + d) * T_ + t0 + dh] = tile[dh][tl + i * 8];
  }
}

// ---------------- flash attention: balanced 32-row Q tiles, wave-pairs split kt ----------------

__global__ __launch_bounds__(256)
void attn_kernel(const u16* __restrict__ c1, const u16* __restrict__ vT,
                 u16* __restrict__ o_bh) {
  __shared__ __align__(16) u16 Qs[32 * 64];
  __shared__ __align__(16) u16 Ks[2][64 * 64];
  __shared__ __align__(16) u16 Vs[2][64 * 64];
  __shared__ __align__(16) u16 Ps[2][32 * 72];
  __shared__ float Om[2][32][68];
  __shared__ float Ml[2][32], Ll[2][32];
  const int bx = blockIdx.x;
  const int qi = (bx & 1) ? (bx >> 1) : (31 - (bx >> 1));
  const int bh = blockIdx.y;
  const int b = bh >> 3, h = bh & 7;
  const int tid = threadIdx.x;
  const int w = tid >> 6, lane = tid & 63;
  const int ln15 = lane & 15, quad = lane >> 4;
  const int hh = w >> 1, wq = w & 1;
  const int q0 = qi * 32;
  const int nkt = (qi >> 1) + 1;
  const int h0n = (nkt + 1) >> 1;
  const int r8 = lane >> 3;
  const int g8 = ((lane & 7) ^ ((lane >> 3) & 7)) * 8;
  const int swz = ln15 & 7;

  async_cp16(c1 + (size_t)(b * T_ + q0 + w * 8 + r8) * N1 + h * DH_ + g8,
             (char*)Qs + w * 1024);

  floatx4 O[4];
  float m_st[4], l_st[4];
  #pragma unroll
  for (int j = 0; j < 4; ++j) {
    O[j] = (floatx4){0.f, 0.f, 0.f, 0.f};
    m_st[j] = -3e38f; l_st[j] = 0.f;
  }
  const int qrow = q0 + wq * 16 + quad * 4;

  for (int j = 0; j < h0n; ++j) {
    const int myt = hh ? (h0n + j) : j;
    const bool act = (hh == 0) || (h0n + j < nkt);
    __syncthreads();
    if (w < 2 || h0n + j < nkt) {
      const int tk = (w < 2 ? j : h0n + j) * 64;
      if ((w & 1) == 0) {
        #pragma unroll
        for (int i = 0; i < 8; ++i)
          async_cp16(c1 + (size_t)(b * T_ + tk + i * 8 + r8) * N1 + 512 + h * DH_ + g8,
                     (char*)Ks[w >> 1] + i * 1024);
      } else {
        #pragma unroll
        for (int i = 0; i < 8; ++i)
          async_cp16(vT + (size_t)((b * H_ + h) * DH_ + i * 8 + r8) * T_ + tk + g8,
                     (char*)Vs[w >> 1] + i * 1024);
      }
    }
    __builtin_amdgcn_s_waitcnt(0);
    __syncthreads();

    float p[4][4];
    if (act) {
      const int tk0 = myt * 64;
      floatx4 S[4];
      #pragma unroll
      for (int nt = 0; nt < 4; ++nt) S[nt] = (floatx4){0.f, 0.f, 0.f, 0.f};
      #pragma unroll
      for (int ks = 0; ks < 2; ++ks) {
        bf16x8 a = *(const bf16x8*)(Qs + (wq * 16 + ln15) * 64 + (((ks * 4 + quad) ^ swz)) * 8);
        #pragma unroll
        for (int nt = 0; nt < 4; ++nt) {
          bf16x8 bv = *(const bf16x8*)(&Ks[hh][(nt * 16 + ln15) * 64 + (((ks * 4 + quad) ^ swz)) * 8]);
          S[nt] = __builtin_amdgcn_mfma_f32_16x16x32_bf16(a, bv, S[nt], 0, 0, 0);
        }
      }
      float rmax[4], alpha[4], rsum[4];
      #pragma unroll
      for (int r = 0; r < 4; ++r) rmax[r] = -3e38f;
      #pragma unroll
      for (int nt = 0; nt < 4; ++nt) {
        int col = tk0 + nt * 16 + ln15;
        #pragma unroll
        for (int r = 0; r < 4; ++r) {
          float s = S[nt][r] * 0.125f;
          if (col > qrow + r) s = -3e38f;
          p[nt][r] = s;
          rmax[r] = fmaxf(rmax[r], s);
        }
      }
      #pragma unroll
      for (int r = 0; r < 4; ++r) {
        #pragma unroll
        for (int off = 1; off < 16; off <<= 1)
          rmax[r] = fmaxf(rmax[r], __shfl_xor(rmax[r], off));
        float mn = fmaxf(m_st[r], rmax[r]);
        alpha[r] = __expf(m_st[r] - mn);
        m_st[r] = mn;
        rsum[r] = 0.f;
      }
      #pragma unroll
      for (int nt = 0; nt < 4; ++nt)
        #pragma unroll
        for (int r = 0; r < 4; ++r) {
          float e = __expf(p[nt][r] - m_st[r]);
          p[nt][r] = e;
          rsum[r] += e;
        }
      #pragma unroll
      for (int r = 0; r < 4; ++r) {
        #pragma unroll
        for (int off = 1; off < 16; off <<= 1)
          rsum[r] += __shfl_xor(rsum[r], off);
        l_st[r] = l_st[r] * alpha[r] + rsum[r];
      }
      #pragma unroll
      for (int nt = 0; nt < 4; ++nt)
        #pragma unroll
        for (int r = 0; r < 4; ++r) O[nt][r] *= alpha[r];
      #pragma unroll
      for (int nt = 0; nt < 4; ++nt)
        #pragma unroll
        for (int r = 0; r < 4; ++r)
          Ps[hh][(wq * 16 + quad * 4 + r) * 72 + nt * 16 + ln15] = f2bf(p[nt][r]);
    }
    __syncthreads();
    if (act) {
      #pragma unroll
      for (int ks = 0; ks < 2; ++ks) {
        bf16x8 a = *(const bf16x8*)(&Ps[hh][(wq * 16 + ln15) * 72 + ks * 32 + quad * 8]);
        #pragma unroll
        for (int nt = 0; nt < 4; ++nt) {
          bf16x8 bv = *(const bf16x8*)(&Vs[hh][(nt * 16 + ln15) * 64 + (((ks * 4 + quad) ^ swz)) * 8]);
          O[nt] = __builtin_amdgcn_mfma_f32_16x16x32_bf16(a, bv, O[nt], 0, 0, 0);
        }
      }
    }
  }

  #pragma unroll
  for (int nt = 0; nt < 4; ++nt)
    #pragma unroll
    for (int r = 0; r < 4; ++r)
      Om[hh][wq * 16 + quad * 4 + r][nt * 16 + ln15] = O[nt][r];
  if (ln15 == 0) {
    #pragma unroll
    for (int r = 0; r < 4; ++r) {
      Ml[hh][wq * 16 + quad * 4 + r] = m_st[r];
      Ll[hh][wq * 16 + quad * 4 + r] = l_st[r];
    }
  }
  __syncthreads();

  const int rr = tid >> 3, cg = (tid & 7) * 8;
  float m0 = Ml[0][rr], m1 = Ml[1][rr];
  float l0 = Ll[0][rr], l1 = Ll[1][rr];
  float m = fmaxf(m0, m1);
  float a0 = __expf(m0 - m), a1 = __expf(m1 - m);
  float inv = 1.f / (l0 * a0 + l1 * a1);
  union { u16 s[8]; uint4 v; } o;
  #pragma unroll
  for (int cc = 0; cc < 8; ++cc)
    o.s[cc] = f2bf((Om[0][rr][cg + cc] * a0 + Om[1][rr][cg + cc] * a1) * inv);
  *(uint4*)(o_bh + ((size_t)((b * 8 + h) * 1024 + q0 + rr)) * 64 + cg) = o.v;
}

// ---------------- launch ----------------

extern "C" void kernel_launch(void* const* d_in, const int* in_sizes, int n_in,
                              void* d_out, int out_size, void* d_ws, size_t ws_size,
                              hipStream_t stream) {
  const float* x  = (const float*)d_in[0];
  const float* Wq = (const float*)d_in[1];
  const float* Wk = (const float*)d_in[2];
  const float* Wv = (const float*)d_in[3];
  const float* Ws = (const float*)d_in[4];
  const float* Wd = (const float*)d_in[5];
  const float* Wo = (const float*)d_in[6];
  float* out = (float*)d_out;

  char* ws = (char*)d_ws;
  u16*   WoT  = (u16*)(ws + 0);            //  5,242,880
  u16*   xb   = (u16*)(ws + 5242880);      //  4,194,304
  u16*   WT   = (u16*)(ws + 9437184);      //  7,340,032  (end 16,777,216)
  u16*   c1   = (u16*)(ws + 16777216);     // 14,680,064  (end 31,457,280)
  float* ssg  = (float*)(ws + 31457280);   //    327,680
  u64*   sdb  = (u64*)(ws + 31784960);     //     16,384
  u16*   o_bh = (u16*)(ws + 31801344);     //  2,097,152  (end 33,898,496)
  u16*   vT   = (u16*)(ws + 33898496);     //  2,097,152  (end 35,995,648)
  u16*   Pk   = (u16*)(ws + 35995648);     // 16,777,216  (end 52,772,864)

  // logits+topk (blocks 0..255, dispatched first) + weight prep (256..6399)
  preamble_kernel<<<6400, 256, 0, stream>>>(x, Wq, Wk, Wv, Ws, Wd, Wo,
                                            WT, WoT, ssg, sdb, xb);

  // c1 = xb @ WT^T : M=2048, N=3584, K=1024, BK=64
  gemm4w_kernel<<<dim3(16, 28), 256, 0, stream>>>(xb, WT, c1, N1, 1024);

  vmix_tr_kernel<<<dim3(16, 32, 2), 256, 0, stream>>>(c1, ssg, vT);

  attn_kernel<<<dim3(32, 16), 256, 0, stream>>>(c1, vT, o_bh);

  // out = (sd ? o : 0) @ WoT^T : split-K=4, BK=64, bf16 partials
  gemm2f_kernel<<<dim3(16, 8, 4), 256, 0, stream>>>(o_bh, WoT, sdb, Pk);
  reduce4_kernel<<<1024, 256, 0, stream>>>(Pk, out);
}